// Round 4
// baseline (3705.523 us; speedup 1.0000x reference)
//
#include <hip/hip_runtime.h>
#include <hip/hip_bf16.h>
#include <math.h>

#define SSH 4
#define SCALE 0.17677669529663687f  // 1/sqrt(32)

typedef __bf16 bf16x8 __attribute__((ext_vector_type(8)));
typedef float  f32x4  __attribute__((ext_vector_type(4)));

#define MFMA16(a,b,c) __builtin_amdgcn_mfma_f32_16x16x32_bf16((a),(b),(c),0,0,0)

static __device__ __forceinline__ bf16x8 ldfrag(const __bf16* p){
    return *reinterpret_cast<const bf16x8*>(p);
}

// ---------------- K1: LN1 + shift + window partition + qkv GEMM (MFMA) -> S (bf16, with bias)
__global__ __launch_bounds__(256,3) void k_qkv(const float* __restrict__ x,
        const float* __restrict__ n1g, const float* __restrict__ n1b,
        const float* __restrict__ qkv_w, const float* __restrict__ qkv_b,
        __bf16* __restrict__ S){
    __shared__ __align__(16) __bf16 xw[64*200];
    __shared__ __align__(16) __bf16 Wt[192*72];
    int tid = threadIdx.x;
    int win = blockIdx.x;
    int bb = win>>8, rem = win&255, wh = rem>>4, wwi = rem&15;
    {   // LN1 on shifted window tokens (4 threads per token)
        int tok = tid>>2, part = tid&3;
        int r = tok>>3, c = tok&7;
        int sh = (wh*8 + r + SSH)&127, sw = (wwi*8 + c + SSH)&127;
        const float* srcp = x + (((size_t)(bb*128+sh))*128 + sw)*192 + part*48;
        float v[48];
        #pragma unroll
        for (int i=0;i<12;i++){
            float4 t4 = *reinterpret_cast<const float4*>(srcp + i*4);
            v[i*4]=t4.x; v[i*4+1]=t4.y; v[i*4+2]=t4.z; v[i*4+3]=t4.w;
        }
        float s=0.f, ss=0.f;
        #pragma unroll
        for (int i=0;i<48;i++){ s+=v[i]; ss+=v[i]*v[i]; }
        s  += __shfl_xor(s,1);  s  += __shfl_xor(s,2);
        ss += __shfl_xor(ss,1); ss += __shfl_xor(ss,2);
        float mean = s*(1.f/192.f);
        float rstd = rsqrtf(ss*(1.f/192.f) - mean*mean + 1e-5f);
        #pragma unroll
        for (int i=0;i<48;i++){
            int ch = part*48 + i;
            xw[tok*200 + ch] = (__bf16)((v[i]-mean)*rstd*n1g[ch] + n1b[ch]);
        }
    }
    int lane = tid&63, w = tid>>6, lr = lane&15, lg = lane>>4;
    for (int nc=0; nc<3; nc++){
        f32x4 acc[4][3];
        #pragma unroll
        for (int m=0;m<4;m++)
            #pragma unroll
            for (int n=0;n<3;n++) acc[m][n] = (f32x4){0.f,0.f,0.f,0.f};
        for (int kc=0; kc<3; kc++){
            __syncthreads();
            #pragma unroll
            for (int i=0;i<48;i++){
                int e = tid + i*256;            // 12288 = 64 k2 x 192 j
                int k2 = e/192, j = e - k2*192;
                Wt[j*72 + k2] = (__bf16)qkv_w[(size_t)(kc*64+k2)*576 + nc*192 + j];
            }
            __syncthreads();
            #pragma unroll
            for (int kk=0; kk<2; kk++){
                int ko = kc*64 + kk*32 + lg*8;
                bf16x8 a[4];
                #pragma unroll
                for (int m=0;m<4;m++) a[m] = ldfrag(&xw[(16*m+lr)*200 + ko]);
                int klo = kk*32 + lg*8;
                bf16x8 bfr[3];
                #pragma unroll
                for (int n=0;n<3;n++) bfr[n] = ldfrag(&Wt[(48*w+16*n+lr)*72 + klo]);
                #pragma unroll
                for (int m=0;m<4;m++)
                    #pragma unroll
                    for (int n=0;n<3;n++) acc[m][n] = MFMA16(a[m], bfr[n], acc[m][n]);
            }
        }
        #pragma unroll
        for (int n=0;n<3;n++){
            int col = nc*192 + 48*w + 16*n + lr;
            float bias = qkv_b[col];
            #pragma unroll
            for (int m=0;m<4;m++)
                #pragma unroll
                for (int r=0;r<4;r++){
                    int row = 16*m + 4*lg + r;
                    S[(size_t)(win*64+row)*576 + col] = (__bf16)(acc[m][n][r] + bias);
                }
        }
    }
}

// ---------------- K2: spatial window attention from S -> Bbuf (d_out) --------
__global__ __launch_bounds__(256,3) void k_spatial(const __bf16* __restrict__ S,
        const float* __restrict__ relt, const float* __restrict__ mask,
        float* __restrict__ Bbuf){
    __shared__ __align__(16) float qs[64*36], ks[64*36], vs[64*36];
    __shared__ float Sc[64*66];
    int tid = threadIdx.x;
    int win = blockIdx.x;
    int widx = win & 255;
    int n_o = tid>>2;
    int d0  = (tid&3)*8;
    int c0  = (tid&3)*16;
    for (int h=0; h<6; h++){
        __syncthreads();
        #pragma unroll
        for (int i=0;i<24;i++){
            int e = tid + i*256;           // 6144 = 3m x 64row x 32d
            int m = e>>11, rem2 = e&2047, row = rem2>>5, d = rem2&31;
            float v = (float)S[((size_t)win*64+row)*576 + m*192 + h*32 + d];
            float* dst = (m==0)?qs:((m==1)?ks:vs);
            dst[row*36+d] = v;
        }
        __syncthreads();
        float qreg[32];
        #pragma unroll
        for (int i=0;i<8;i++){
            float4 q4 = *reinterpret_cast<const float4*>(&qs[n_o*36 + i*4]);
            qreg[i*4]=q4.x; qreg[i*4+1]=q4.y; qreg[i*4+2]=q4.z; qreg[i*4+3]=q4.w;
        }
        float sc[16];
        #pragma unroll
        for (int j=0;j<16;j++){
            int col = c0 + j;
            float dot = 0.f;
            #pragma unroll
            for (int i=0;i<8;i++){
                float4 k4 = *reinterpret_cast<const float4*>(&ks[col*36 + i*4]);
                dot += qreg[i*4]*k4.x + qreg[i*4+1]*k4.y + qreg[i*4+2]*k4.z + qreg[i*4+3]*k4.w;
            }
            int dr = (n_o>>3) - (col>>3) + 7;
            int dc = (n_o&7)  - (col&7)  + 7;
            float bias = relt[(dr*15 + dc)*6 + h];
            float mk   = mask[((widx*64 + n_o)<<6) + col];
            sc[j] = dot*SCALE + bias + mk;
        }
        float mx = sc[0];
        #pragma unroll
        for (int j=1;j<16;j++) mx = fmaxf(mx, sc[j]);
        mx = fmaxf(mx, __shfl_xor(mx,1));
        mx = fmaxf(mx, __shfl_xor(mx,2));
        float sum = 0.f;
        #pragma unroll
        for (int j=0;j<16;j++){ sc[j] = __expf(sc[j]-mx); sum += sc[j]; }
        sum += __shfl_xor(sum,1);
        sum += __shfl_xor(sum,2);
        float inv = 1.f/sum;
        #pragma unroll
        for (int j=0;j<16;j++) Sc[n_o*66 + c0 + j] = sc[j]*inv;
        __syncthreads();
        float oacc[8];
        #pragma unroll
        for (int j=0;j<8;j++) oacc[j]=0.f;
        for (int mcol=0; mcol<64; mcol++){
            float p = Sc[n_o*66 + mcol];
            float4 v0 = *reinterpret_cast<const float4*>(&vs[mcol*36 + d0]);
            float4 v1 = *reinterpret_cast<const float4*>(&vs[mcol*36 + d0 + 4]);
            oacc[0]+=p*v0.x; oacc[1]+=p*v0.y; oacc[2]+=p*v0.z; oacc[3]+=p*v0.w;
            oacc[4]+=p*v1.x; oacc[5]+=p*v1.y; oacc[6]+=p*v1.z; oacc[7]+=p*v1.w;
        }
        float* outp = Bbuf + ((size_t)win*64 + n_o)*192 + h*32 + d0;
        *reinterpret_cast<float4*>(outp)   = make_float4(oacc[0],oacc[1],oacc[2],oacc[3]);
        *reinterpret_cast<float4*>(outp+4) = make_float4(oacc[4],oacc[5],oacc[6],oacc[7]);
    }
}

// ------- K3: Fourier branch per (window, head): FFT(S_h) -> attn -> iFFT, += into Bbuf
__global__ __launch_bounds__(256,3) void k_fattn(const __bf16* __restrict__ S,
        const float* __restrict__ qkv_b, float* __restrict__ Bbuf){
    __shared__ __align__(16) float2 qf[40*33], kf[40*33], vf[40*33]; // 31,680 B
    __shared__ __align__(16) float U[5248];                         // 20,992 B union
    __shared__ float csl[8], snl[8];
    int tid = threadIdx.x;
    int win = blockIdx.x / 6;
    int h   = blockIdx.x - win*6;
    if (tid < 8){
        float ang = (float)tid * 0.78539816339744831f;  // 2*pi*t/8
        csl[tid] = cosf(ang); snl[tid] = sinf(ang);
    }
    int d = tid&31, g = tid>>5;    // d: head-dim lane, g: 0..7 group
    __syncthreads();
    // stage-A twiddles: w_r = e^{-2pi i g r/8}
    float wrr[8], wri[8];
    {
        float cu = csl[g], su = snl[g];
        float wr = 1.f, wi = 0.f;
        #pragma unroll
        for (int r=0;r<8;r++){
            wrr[r]=wr; wri[r]=wi;
            float nr = wr*cu + wi*su, ni = wi*cu - wr*su;
            wr=nr; wi=ni;
        }
    }
    __bf16* Sh = (__bf16*)U;                               // [64][36] bf16, 4608 B
    float2* Tc = reinterpret_cast<float2*>(U + 1152);      // [8u][8c][32d], 16384 B
    for (int m=0;m<3;m++){
        __syncthreads();
        #pragma unroll
        for (int i=0;i<8;i++){
            int e = tid + i*256;           // 2048
            int p = e>>5, dd = e&31;
            Sh[p*36+dd] = S[((size_t)win*64+p)*576 + m*192 + h*32 + dd];
        }
        __syncthreads();
        // stage A (row FFT): T[u=g][c][d] = sum_r Sh[r*8+c][d] * e^{-2pi i g r/8}
        #pragma unroll
        for (int c=0;c<8;c++){
            float tre=0.f, tim=0.f;
            #pragma unroll
            for (int r=0;r<8;r++){
                float s = (float)Sh[(r*8+c)*36 + d];
                tre += s*wrr[r]; tim += s*wri[r];
            }
            Tc[(g*8+c)*32 + d] = make_float2(tre, tim);
        }
        __syncthreads();
        // stage B (col FFT): n = g*5+v; includes ortho 1/8 and exact bias fix
        float bias = qkv_b[m*192 + h*32 + d];
        float2* dstf = (m==0)?qf:((m==1)?kf:vf);
        #pragma unroll
        for (int v=0;v<5;v++){
            float cv = csl[v], sv = snl[v];
            float wr=1.f, wi=0.f, ar=0.f, ai=0.f;
            #pragma unroll
            for (int c=0;c<8;c++){
                float2 t = Tc[(g*8+c)*32 + d];
                ar += t.x*wr - t.y*wi;
                ai += t.x*wi + t.y*wr;
                float nr = wr*cv + wi*sv, ni = wi*cv - wr*sv;  // *= e^{-2pi i v/8}
                wr=nr; wi=ni;
            }
            int n = g*5+v;
            // S has bias: F.S = F.S_nb + 8b at n==0 (re). want F.S_nb + b(1+i)
            float cre = ar*0.125f + ((n==0)? -7.f*bias : bias);
            float cim = ai*0.125f + bias;
            dstf[n*33+d] = make_float2(cre, cim);
        }
    }
    __syncthreads();
    float* Smat = U + 2560;        // 1600 floats @ byte 10240
    for (int o=tid; o<1600; o+=256){
        unsigned n = (unsigned)o/40u; int mc = o - (int)n*40;
        float sre=0.f, sim=0.f;
        #pragma unroll
        for (int dd=0; dd<32; dd++){
            float2 q = qf[n*33+dd];
            float2 k = kf[mc*33+dd];
            sre += q.x*k.x - q.y*k.y;
            sim += q.x*k.y + q.y*k.x;
        }
        Smat[o] = SCALE * sqrtf(sre*sre + sim*sim);
    }
    __syncthreads();
    if (tid < 160){
        int row = tid>>2, part = tid&3, e0 = part*10;
        float mx = -1e30f;
        #pragma unroll
        for (int j=0;j<10;j++) mx = fmaxf(mx, Smat[row*40 + e0 + j]);
        mx = fmaxf(mx, __shfl_xor(mx,1));
        mx = fmaxf(mx, __shfl_xor(mx,2));
        float ex[10]; float sum=0.f;
        #pragma unroll
        for (int j=0;j<10;j++){ ex[j] = __expf(Smat[row*40+e0+j]-mx); sum += ex[j]; }
        sum += __shfl_xor(sum,1);
        sum += __shfl_xor(sum,2);
        float inv = 1.f/sum;
        #pragma unroll
        for (int j=0;j<10;j++) Smat[row*40+e0+j] = ex[j]*inv;
    }
    __syncthreads();
    // PV (P real): rv[n][d] = sum_mc P[n,mc] * vf[mc][d]
    float2* rv = reinterpret_cast<float2*>(U);   // [40][32] @ byte 0
    {
        float ar[5], ai[5];
        #pragma unroll
        for (int j=0;j<5;j++){ ar[j]=0.f; ai[j]=0.f; }
        for (int mc=0; mc<40; mc++){
            float2 v = vf[mc*33+d];
            #pragma unroll
            for (int j=0;j<5;j++){
                float s = Smat[(g*5+j)*40 + mc];
                ar[j] += s*v.x; ai[j] += s*v.y;
            }
        }
        #pragma unroll
        for (int j=0;j<5;j++) rv[(g*5+j)*32 + d] = make_float2(ar[j], ai[j]);
    }
    // iFFT (ortho, numpy irfftn semantics), two-stage, split over u-halves
    float2* Tc2 = reinterpret_cast<float2*>(U + 2560);  // 8192 B over dead Smat
    float xacc[8];
    #pragma unroll
    for (int c=0;c<8;c++) xacc[c]=0.f;
    float wur = 1.f, wui = 0.f;                 // e^{+2pi i u g/8}, advanced over u
    float crr = csl[g], srr = snl[g];
    for (int half=0; half<2; half++){
        __syncthreads();
        {   // stage 1: Tc2[u][c][d] = sum_v wv * G[u,v,d] * e^{+2pi i v c/8}
            int u = half*4 + (g&3);
            int cbase = (g>>2)*4;
            #pragma unroll
            for (int cc=0; cc<4; cc++){
                int c = cbase + cc;
                float stepr = csl[c], stepi = snl[c];
                float wr=1.f, wi=0.f, ar=0.f, ai=0.f;
                #pragma unroll
                for (int v=0; v<5; v++){
                    float2 Gv = rv[(u*5+v)*32 + d];
                    float wv = (v>=1 && v<=3)? 2.f : 1.f;
                    float gx = Gv.x*wv, gy = Gv.y*wv;
                    ar += gx*wr - gy*wi;
                    ai += gx*wi + gy*wr;
                    float nr = wr*stepr - wi*stepi, ni = wr*stepi + wi*stepr;
                    wr=nr; wi=ni;
                }
                Tc2[((u&3)*8 + c)*32 + d] = make_float2(ar, ai);
            }
        }
        __syncthreads();
        {   // stage 2: x[r=g][c][d] += Re{ Tc2[u][c][d] * e^{+2pi i u g/8} }
            #pragma unroll
            for (int uu=0; uu<4; uu++){
                float wrc = wur, wic = wui;
                #pragma unroll
                for (int c=0;c<8;c++){
                    float2 t = Tc2[(uu*8 + c)*32 + d];
                    xacc[c] += t.x*wrc - t.y*wic;
                }
                float nr = wur*crr - wui*srr, ni = wur*srr + wui*crr;
                wur=nr; wui=ni;
            }
        }
    }
    #pragma unroll
    for (int c=0;c<8;c++){
        size_t idx = ((size_t)win*64 + g*8 + c)*192 + h*32 + d;
        Bbuf[idx] += 0.125f*xacc[c];
    }
}

// ---------------- K4: proj (MFMA) + window reverse + unshift + residual -> X1
__global__ __launch_bounds__(256,3) void k_proj(const float* __restrict__ Bbuf,
        const float* __restrict__ x, const float* __restrict__ proj_w,
        const float* __restrict__ proj_b, float* __restrict__ X1){
    __shared__ __align__(16) __bf16 xt[64*200];
    __shared__ __align__(16) __bf16 Wt[192*72];
    int tid = threadIdx.x;
    int win = blockIdx.x;
    #pragma unroll
    for (int i=0;i<48;i++){
        int e = tid + i*256;               // 12288
        int row = e/192, ch = e - row*192;
        xt[row*200 + ch] = (__bf16)Bbuf[(size_t)win*12288 + e];
    }
    int lane = tid&63, w = tid>>6, lr = lane&15, lg = lane>>4;
    f32x4 acc[4][3];
    #pragma unroll
    for (int m=0;m<4;m++)
        #pragma unroll
        for (int n=0;n<3;n++) acc[m][n] = (f32x4){0.f,0.f,0.f,0.f};
    for (int kc=0; kc<3; kc++){
        __syncthreads();
        #pragma unroll
        for (int i=0;i<48;i++){
            int e = tid + i*256;
            int k2 = e/192, j = e - k2*192;
            Wt[j*72 + k2] = (__bf16)proj_w[(size_t)(kc*64+k2)*192 + j];
        }
        __syncthreads();
        #pragma unroll
        for (int kk=0; kk<2; kk++){
            int ko = kc*64 + kk*32 + lg*8;
            bf16x8 a[4];
            #pragma unroll
            for (int m=0;m<4;m++) a[m] = ldfrag(&xt[(16*m+lr)*200 + ko]);
            int klo = kk*32 + lg*8;
            bf16x8 bfr[3];
            #pragma unroll
            for (int n=0;n<3;n++) bfr[n] = ldfrag(&Wt[(48*w+16*n+lr)*72 + klo]);
            #pragma unroll
            for (int m=0;m<4;m++)
                #pragma unroll
                for (int n=0;n<3;n++) acc[m][n] = MFMA16(a[m], bfr[n], acc[m][n]);
        }
    }
    int bb = win>>8, rem = win&255, wh = rem>>4, wwi = rem&15;
    #pragma unroll
    for (int m=0;m<4;m++)
        #pragma unroll
        for (int r=0;r<4;r++){
            int t = 16*m + 4*lg + r;
            int p = wh*8 + (t>>3), q = wwi*8 + (t&7);
            int hh = (p+SSH)&127, w2 = (q+SSH)&127;
            size_t pixb = (((size_t)bb*128 + hh)*128 + w2)*192;
            #pragma unroll
            for (int n=0;n<3;n++){
                int col = 48*w + 16*n + lr;
                X1[pixb + col] = acc[m][n][r] + proj_b[col] + x[pixb + col];
            }
        }
}

// ---------------- K5: LN2 + fc1(MFMA) + exact GELU + fc2(MFMA) + residual ----
__global__ __launch_bounds__(256,2) void k_mlp(const float* __restrict__ X1,
        const float* __restrict__ g2, const float* __restrict__ b2v,
        const float* __restrict__ fc1w, const float* __restrict__ fc1b,
        const float* __restrict__ fc2w, const float* __restrict__ fc2b,
        float* __restrict__ out){
    __shared__ __align__(16) __bf16 xln[64*200];
    __shared__ __align__(16) __bf16 Wt[192*72];
    __shared__ __align__(16) __bf16 hbuf[64*200];
    int tid = threadIdx.x;
    size_t base = (size_t)blockIdx.x*64;
    {
        int tok = tid>>2, part = tid&3;
        const float* srcp = X1 + (base + tok)*192 + part*48;
        float v[48];
        #pragma unroll
        for (int i=0;i<12;i++){
            float4 t4 = *reinterpret_cast<const float4*>(srcp + i*4);
            v[i*4]=t4.x; v[i*4+1]=t4.y; v[i*4+2]=t4.z; v[i*4+3]=t4.w;
        }
        float s=0.f, ss=0.f;
        #pragma unroll
        for (int i=0;i<48;i++){ s+=v[i]; ss+=v[i]*v[i]; }
        s  += __shfl_xor(s,1);  s  += __shfl_xor(s,2);
        ss += __shfl_xor(ss,1); ss += __shfl_xor(ss,2);
        float mean = s*(1.f/192.f);
        float rstd = rsqrtf(ss*(1.f/192.f) - mean*mean + 1e-5f);
        #pragma unroll
        for (int i=0;i<48;i++){
            int ch = part*48 + i;
            xln[tok*200 + ch] = (__bf16)((v[i]-mean)*rstd*g2[ch] + b2v[ch]);
        }
    }
    int lane = tid&63, w = tid>>6, lr = lane&15, lg = lane>>4;
    f32x4 acc2[4][3];
    #pragma unroll
    for (int m=0;m<4;m++)
        #pragma unroll
        for (int n=0;n<3;n++) acc2[m][n] = (f32x4){0.f,0.f,0.f,0.f};
    for (int hc=0; hc<4; hc++){
        // ---- fc1 chunk: h[64][192] = xln @ W1[:, hc*192..]
        f32x4 acc1[4][3];
        #pragma unroll
        for (int m=0;m<4;m++)
            #pragma unroll
            for (int n=0;n<3;n++) acc1[m][n] = (f32x4){0.f,0.f,0.f,0.f};
        for (int kc=0; kc<3; kc++){
            __syncthreads();
            #pragma unroll
            for (int i=0;i<48;i++){
                int e = tid + i*256;
                int k2 = e/192, j = e - k2*192;
                Wt[j*72 + k2] = (__bf16)fc1w[(size_t)(kc*64+k2)*768 + hc*192 + j];
            }
            __syncthreads();
            #pragma unroll
            for (int kk=0; kk<2; kk++){
                int ko = kc*64 + kk*32 + lg*8;
                bf16x8 a[4];
                #pragma unroll
                for (int m=0;m<4;m++) a[m] = ldfrag(&xln[(16*m+lr)*200 + ko]);
                int klo = kk*32 + lg*8;
                bf16x8 bfr[3];
                #pragma unroll
                for (int n=0;n<3;n++) bfr[n] = ldfrag(&Wt[(48*w+16*n+lr)*72 + klo]);
                #pragma unroll
                for (int m=0;m<4;m++)
                    #pragma unroll
                    for (int n=0;n<3;n++) acc1[m][n] = MFMA16(a[m], bfr[n], acc1[m][n]);
            }
        }
        // GELU -> hbuf
        #pragma unroll
        for (int n=0;n<3;n++){
            int jcol = 48*w + 16*n + lr;
            float b1 = fc1b[hc*192 + jcol];
            #pragma unroll
            for (int m=0;m<4;m++)
                #pragma unroll
                for (int r=0;r<4;r++){
                    float xv = acc1[m][n][r] + b1;
                    float gv = 0.5f*xv*(1.f + erff(xv*0.70710678118654752f));
                    hbuf[(16*m + 4*lg + r)*200 + jcol] = (__bf16)gv;
                }
        }
        // ---- fc2 chunk: acc2 += h @ W2[hc*192.., :]
        for (int kc=0; kc<3; kc++){
            __syncthreads();
            #pragma unroll
            for (int i=0;i<48;i++){
                int e = tid + i*256;
                int j2 = e/192, c = e - j2*192;
                Wt[c*72 + j2] = (__bf16)fc2w[(size_t)(hc*192 + kc*64 + j2)*192 + c];
            }
            __syncthreads();
            #pragma unroll
            for (int kk=0; kk<2; kk++){
                int ko = kc*64 + kk*32 + lg*8;
                bf16x8 a[4];
                #pragma unroll
                for (int m=0;m<4;m++) a[m] = ldfrag(&hbuf[(16*m+lr)*200 + ko]);
                int klo = kk*32 + lg*8;
                bf16x8 bfr[3];
                #pragma unroll
                for (int n=0;n<3;n++) bfr[n] = ldfrag(&Wt[(48*w+16*n+lr)*72 + klo]);
                #pragma unroll
                for (int m=0;m<4;m++)
                    #pragma unroll
                    for (int n=0;n<3;n++) acc2[m][n] = MFMA16(a[m], bfr[n], acc2[m][n]);
            }
        }
    }
    #pragma unroll
    for (int n=0;n<3;n++){
        int col = 48*w + 16*n + lr;
        float b2 = fc2b[col];
        #pragma unroll
        for (int m=0;m<4;m++)
            #pragma unroll
            for (int r=0;r<4;r++){
                size_t t = base + 16*m + 4*lg + r;
                out[t*192 + col] = acc2[m][n][r] + b2 + X1[t*192 + col];
            }
    }
}

extern "C" void kernel_launch(void* const* d_in, const int* in_sizes, int n_in,
                              void* d_out, int out_size, void* d_ws, size_t ws_size,
                              hipStream_t stream) {
    const float* x     = (const float*)d_in[0];
    const float* mask  = (const float*)d_in[1];
    const float* n1g   = (const float*)d_in[2];
    const float* n1b   = (const float*)d_in[3];
    const float* qkvw  = (const float*)d_in[4];
    const float* qkvb  = (const float*)d_in[5];
    const float* relt  = (const float*)d_in[6];
    const float* projw = (const float*)d_in[7];
    const float* projb = (const float*)d_in[8];
    const float* n2g   = (const float*)d_in[9];
    const float* n2b   = (const float*)d_in[10];
    const float* fc1w  = (const float*)d_in[11];
    const float* fc1b  = (const float*)d_in[12];
    const float* fc2w  = (const float*)d_in[13];
    const float* fc2b  = (const float*)d_in[14];
    float* out = (float*)d_out;

    __bf16* Sb = (__bf16*)d_ws;                                // 150,994,944 B
    float*  X1 = (float*)((char*)d_ws + 150994944);            // 100,663,296 B

    k_qkv    <<<2048,  256, 0, stream>>>(x, n1g, n1b, qkvw, qkvb, Sb);
    k_spatial<<<2048,  256, 0, stream>>>(Sb, relt, mask, out);
    k_fattn  <<<12288, 256, 0, stream>>>(Sb, qkvb, out);
    k_proj   <<<2048,  256, 0, stream>>>(out, x, projw, projb, X1);
    k_mlp    <<<2048,  256, 0, stream>>>(X1, n2g, n2b, fc1w, fc1b, fc2w, fc2b, out);
}

// Round 5
// 1184.000 us; speedup vs baseline: 3.1297x; 3.1297x over previous
//
#include <hip/hip_runtime.h>
#include <hip/hip_bf16.h>
#include <math.h>

#define SSH 4
#define SCALE 0.17677669529663687f  // 1/sqrt(32)

typedef __bf16 bf16x8 __attribute__((ext_vector_type(8)));
typedef unsigned short ushort8 __attribute__((ext_vector_type(8)));
typedef float  f32x4  __attribute__((ext_vector_type(4)));

#define MFMA16(a,b,c) __builtin_amdgcn_mfma_f32_16x16x32_bf16((a),(b),(c),0,0,0)

static __device__ __forceinline__ bf16x8 ldfrag(const __bf16* p){
    return *reinterpret_cast<const bf16x8*>(p);
}

// ---------------- K0: weight prep: bf16 + transpose to [N][K] ----------------
__global__ __launch_bounds__(256) void k_prep(const float* __restrict__ qkvw,
        const float* __restrict__ projw, const float* __restrict__ fc1w,
        const float* __restrict__ fc2w, __bf16* __restrict__ Wq,
        __bf16* __restrict__ Wp, __bf16* __restrict__ W1, __bf16* __restrict__ W2){
    int i = blockIdx.x*256 + threadIdx.x;
    if (i < 110592){ int n = i/192, k = i - n*192; Wq[i] = (__bf16)qkvw[k*576 + n]; }
    if (i < 36864) { int n = i/192, k = i - n*192; Wp[i] = (__bf16)projw[k*192 + n]; }
    if (i < 147456){ int n = i/192, k = i - n*192; W1[i] = (__bf16)fc1w[k*768 + n]; }
    if (i < 147456){ int n = i/768, k = i - n*768; W2[i] = (__bf16)fc2w[k*192 + n]; }
}

// ---------------- K1: LN1 + shift + window partition + qkv GEMM (MFMA, pipelined)
__global__ __launch_bounds__(256,2) void k_qkv(const float* __restrict__ x,
        const float* __restrict__ n1g, const float* __restrict__ n1b,
        const __bf16* __restrict__ Wqt, const float* __restrict__ qkv_b,
        __bf16* __restrict__ S){
    __shared__ __align__(16) __bf16 xw[64*200];
    __shared__ __align__(16) __bf16 Wt[192*72];
    int tid = threadIdx.x;
    int win = blockIdx.x;
    int bb = win>>8, rem = win&255, wh = rem>>4, wwi = rem&15;
    {   // LN1 on shifted window tokens (4 threads per token), vectorized pack
        int tok = tid>>2, part = tid&3;
        int r = tok>>3, c = tok&7;
        int sh = (wh*8 + r + SSH)&127, sw = (wwi*8 + c + SSH)&127;
        const float* srcp = x + (((size_t)(bb*128+sh))*128 + sw)*192 + part*48;
        float v[48];
        #pragma unroll
        for (int i=0;i<12;i++){
            float4 t4 = *reinterpret_cast<const float4*>(srcp + i*4);
            v[i*4]=t4.x; v[i*4+1]=t4.y; v[i*4+2]=t4.z; v[i*4+3]=t4.w;
        }
        float s=0.f, ss=0.f;
        #pragma unroll
        for (int i=0;i<48;i++){ s+=v[i]; ss+=v[i]*v[i]; }
        s  += __shfl_xor(s,1);  s  += __shfl_xor(s,2);
        ss += __shfl_xor(ss,1); ss += __shfl_xor(ss,2);
        float mean = s*(1.f/192.f);
        float rstd = rsqrtf(ss*(1.f/192.f) - mean*mean + 1e-5f);
        #pragma unroll
        for (int i8=0;i8<6;i8++){
            bf16x8 pk;
            #pragma unroll
            for (int j=0;j<8;j++){
                int ch = part*48 + i8*8 + j;
                pk[j] = (__bf16)((v[i8*8+j]-mean)*rstd*n1g[ch] + n1b[ch]);
            }
            *reinterpret_cast<bf16x8*>(&xw[tok*200 + part*48 + i8*8]) = pk;
        }
    }
    int lane = tid&63, w = tid>>6, lr = lane&15, lg = lane>>4;
    ushort8 wreg[6];
    // stage s = nc*3 + kc
    auto ldW = [&](int s, ushort8* wr){
        int nc = s/3, kc = s - nc*3;
        #pragma unroll
        for (int i=0;i<6;i++){
            int e = tid + i*256;            // 1536 vec8 units: j = e>>3, k8 = e&7
            int j = e>>3, k8 = e&7;
            wr[i] = *reinterpret_cast<const ushort8*>(
                reinterpret_cast<const unsigned short*>(Wqt) + (size_t)(nc*192+j)*192 + kc*64 + k8*8);
        }
    };
    auto stW = [&](ushort8* wr){
        #pragma unroll
        for (int i=0;i<6;i++){
            int e = tid + i*256;
            int j = e>>3, k8 = e&7;
            *reinterpret_cast<ushort8*>(reinterpret_cast<unsigned short*>(Wt) + j*72 + k8*8) = wr[i];
        }
    };
    ldW(0, wreg);
    __syncthreads();
    stW(wreg);
    __syncthreads();
    f32x4 acc[4][3];
    #pragma unroll
    for (int m=0;m<4;m++)
        #pragma unroll
        for (int n=0;n<3;n++) acc[m][n] = (f32x4){0.f,0.f,0.f,0.f};
    for (int s=0; s<9; s++){
        int nc = s/3, kc = s - nc*3;
        if (s<8) ldW(s+1, wreg);
        #pragma unroll
        for (int kk=0; kk<2; kk++){
            int ko = kc*64 + kk*32 + lg*8;
            bf16x8 a[4];
            #pragma unroll
            for (int m=0;m<4;m++) a[m] = ldfrag(&xw[(16*m+lr)*200 + ko]);
            int klo = kk*32 + lg*8;
            bf16x8 bfr[3];
            #pragma unroll
            for (int n=0;n<3;n++) bfr[n] = ldfrag(&Wt[(48*w+16*n+lr)*72 + klo]);
            #pragma unroll
            for (int m=0;m<4;m++)
                #pragma unroll
                for (int n=0;n<3;n++) acc[m][n] = MFMA16(a[m], bfr[n], acc[m][n]);
        }
        if (kc==2){
            #pragma unroll
            for (int n=0;n<3;n++){
                int col = nc*192 + 48*w + 16*n + lr;
                float bias = qkv_b[col];
                #pragma unroll
                for (int m=0;m<4;m++)
                    #pragma unroll
                    for (int r=0;r<4;r++){
                        int row = 16*m + 4*lg + r;
                        S[(size_t)(win*64+row)*576 + col] = (__bf16)(acc[m][n][r] + bias);
                    }
            }
            #pragma unroll
            for (int m=0;m<4;m++)
                #pragma unroll
                for (int n=0;n<3;n++) acc[m][n] = (f32x4){0.f,0.f,0.f,0.f};
        }
        __syncthreads();
        if (s<8) stW(wreg);
        __syncthreads();
    }
}

// ---------------- K2: spatial window attention from S -> Bbuf (d_out) --------
__global__ __launch_bounds__(256,3) void k_spatial(const __bf16* __restrict__ S,
        const float* __restrict__ relt, const float* __restrict__ mask,
        float* __restrict__ Bbuf){
    __shared__ __align__(16) float qs[64*36], ks[64*36], vs[64*36];
    __shared__ float Sc[64*66];
    int tid = threadIdx.x;
    int win = blockIdx.x;
    int widx = win & 255;
    int n_o = tid>>2;
    int d0  = (tid&3)*8;
    int c0  = (tid&3)*16;
    for (int h=0; h<6; h++){
        __syncthreads();
        #pragma unroll
        for (int i=0;i<24;i++){
            int e = tid + i*256;           // 6144 = 3m x 64row x 32d
            int m = e>>11, rem2 = e&2047, row = rem2>>5, d = rem2&31;
            float v = (float)S[((size_t)win*64+row)*576 + m*192 + h*32 + d];
            float* dst = (m==0)?qs:((m==1)?ks:vs);
            dst[row*36+d] = v;
        }
        __syncthreads();
        float qreg[32];
        #pragma unroll
        for (int i=0;i<8;i++){
            float4 q4 = *reinterpret_cast<const float4*>(&qs[n_o*36 + i*4]);
            qreg[i*4]=q4.x; qreg[i*4+1]=q4.y; qreg[i*4+2]=q4.z; qreg[i*4+3]=q4.w;
        }
        float sc[16];
        #pragma unroll
        for (int j=0;j<16;j++){
            int col = c0 + j;
            float dot = 0.f;
            #pragma unroll
            for (int i=0;i<8;i++){
                float4 k4 = *reinterpret_cast<const float4*>(&ks[col*36 + i*4]);
                dot += qreg[i*4]*k4.x + qreg[i*4+1]*k4.y + qreg[i*4+2]*k4.z + qreg[i*4+3]*k4.w;
            }
            int dr = (n_o>>3) - (col>>3) + 7;
            int dc = (n_o&7)  - (col&7)  + 7;
            float bias = relt[(dr*15 + dc)*6 + h];
            float mk   = mask[((widx*64 + n_o)<<6) + col];
            sc[j] = dot*SCALE + bias + mk;
        }
        float mx = sc[0];
        #pragma unroll
        for (int j=1;j<16;j++) mx = fmaxf(mx, sc[j]);
        mx = fmaxf(mx, __shfl_xor(mx,1));
        mx = fmaxf(mx, __shfl_xor(mx,2));
        float sum = 0.f;
        #pragma unroll
        for (int j=0;j<16;j++){ sc[j] = __expf(sc[j]-mx); sum += sc[j]; }
        sum += __shfl_xor(sum,1);
        sum += __shfl_xor(sum,2);
        float inv = 1.f/sum;
        #pragma unroll
        for (int j=0;j<16;j++) Sc[n_o*66 + c0 + j] = sc[j]*inv;
        __syncthreads();
        float oacc[8];
        #pragma unroll
        for (int j=0;j<8;j++) oacc[j]=0.f;
        for (int mcol=0; mcol<64; mcol++){
            float p = Sc[n_o*66 + mcol];
            float4 v0 = *reinterpret_cast<const float4*>(&vs[mcol*36 + d0]);
            float4 v1 = *reinterpret_cast<const float4*>(&vs[mcol*36 + d0 + 4]);
            oacc[0]+=p*v0.x; oacc[1]+=p*v0.y; oacc[2]+=p*v0.z; oacc[3]+=p*v0.w;
            oacc[4]+=p*v1.x; oacc[5]+=p*v1.y; oacc[6]+=p*v1.z; oacc[7]+=p*v1.w;
        }
        float* outp = Bbuf + ((size_t)win*64 + n_o)*192 + h*32 + d0;
        *reinterpret_cast<float4*>(outp)   = make_float4(oacc[0],oacc[1],oacc[2],oacc[3]);
        *reinterpret_cast<float4*>(outp+4) = make_float4(oacc[4],oacc[5],oacc[6],oacc[7]);
    }
}

// ------- K3: Fourier branch per (window, head): FFT(S_h) -> attn -> iFFT, += into Bbuf
__global__ __launch_bounds__(256,3) void k_fattn(const __bf16* __restrict__ S,
        const float* __restrict__ qkv_b, float* __restrict__ Bbuf){
    __shared__ __align__(16) float2 qf[40*33], kf[40*33], vf[40*33]; // 31,680 B
    __shared__ __align__(16) float U[5248];                         // 20,992 B union
    __shared__ float csl[8], snl[8];
    int tid = threadIdx.x;
    int win = blockIdx.x / 6;
    int h   = blockIdx.x - win*6;
    if (tid < 8){
        float ang = (float)tid * 0.78539816339744831f;  // 2*pi*t/8
        csl[tid] = cosf(ang); snl[tid] = sinf(ang);
    }
    int d = tid&31, g = tid>>5;    // d: head-dim lane, g: 0..7 group
    __syncthreads();
    // stage-A twiddles: w_r = e^{-2pi i g r/8}
    float wrr[8], wri[8];
    {
        float cu = csl[g], su = snl[g];
        float wr = 1.f, wi = 0.f;
        #pragma unroll
        for (int r=0;r<8;r++){
            wrr[r]=wr; wri[r]=wi;
            float nr = wr*cu + wi*su, ni = wi*cu - wr*su;
            wr=nr; wi=ni;
        }
    }
    __bf16* Sh = (__bf16*)U;                               // [64][36] bf16, 4608 B
    float2* Tc = reinterpret_cast<float2*>(U + 1152);      // [8u][8c][32d], 16384 B
    for (int m=0;m<3;m++){
        __syncthreads();
        #pragma unroll
        for (int i=0;i<8;i++){
            int e = tid + i*256;           // 2048
            int p = e>>5, dd = e&31;
            Sh[p*36+dd] = S[((size_t)win*64+p)*576 + m*192 + h*32 + dd];
        }
        __syncthreads();
        // stage A (row FFT): T[u=g][c][d] = sum_r Sh[r*8+c][d] * e^{-2pi i g r/8}
        #pragma unroll
        for (int c=0;c<8;c++){
            float tre=0.f, tim=0.f;
            #pragma unroll
            for (int r=0;r<8;r++){
                float s = (float)Sh[(r*8+c)*36 + d];
                tre += s*wrr[r]; tim += s*wri[r];
            }
            Tc[(g*8+c)*32 + d] = make_float2(tre, tim);
        }
        __syncthreads();
        // stage B (col FFT): n = g*5+v; includes ortho 1/8 and exact bias fix
        float bias = qkv_b[m*192 + h*32 + d];
        float2* dstf = (m==0)?qf:((m==1)?kf:vf);
        #pragma unroll
        for (int v=0;v<5;v++){
            float cv = csl[v], sv = snl[v];
            float wr=1.f, wi=0.f, ar=0.f, ai=0.f;
            #pragma unroll
            for (int c=0;c<8;c++){
                float2 t = Tc[(g*8+c)*32 + d];
                ar += t.x*wr - t.y*wi;
                ai += t.x*wi + t.y*wr;
                float nr = wr*cv + wi*sv, ni = wi*cv - wr*sv;  // *= e^{-2pi i v/8}
                wr=nr; wi=ni;
            }
            int n = g*5+v;
            float cre = ar*0.125f + ((n==0)? -7.f*bias : bias);
            float cim = ai*0.125f + bias;
            dstf[n*33+d] = make_float2(cre, cim);
        }
    }
    __syncthreads();
    float* Smat = U + 2560;        // 1600 floats @ byte 10240
    for (int o=tid; o<1600; o+=256){
        unsigned n = (unsigned)o/40u; int mc = o - (int)n*40;
        float sre=0.f, sim=0.f;
        #pragma unroll
        for (int dd=0; dd<32; dd++){
            float2 q = qf[n*33+dd];
            float2 k = kf[mc*33+dd];
            sre += q.x*k.x - q.y*k.y;
            sim += q.x*k.y + q.y*k.x;
        }
        Smat[o] = SCALE * sqrtf(sre*sre + sim*sim);
    }
    __syncthreads();
    if (tid < 160){
        int row = tid>>2, part = tid&3, e0 = part*10;
        float mx = -1e30f;
        #pragma unroll
        for (int j=0;j<10;j++) mx = fmaxf(mx, Smat[row*40 + e0 + j]);
        mx = fmaxf(mx, __shfl_xor(mx,1));
        mx = fmaxf(mx, __shfl_xor(mx,2));
        float ex[10]; float sum=0.f;
        #pragma unroll
        for (int j=0;j<10;j++){ ex[j] = __expf(Smat[row*40+e0+j]-mx); sum += ex[j]; }
        sum += __shfl_xor(sum,1);
        sum += __shfl_xor(sum,2);
        float inv = 1.f/sum;
        #pragma unroll
        for (int j=0;j<10;j++) Smat[row*40+e0+j] = ex[j]*inv;
    }
    __syncthreads();
    // PV (P real): rv[n][d] = sum_mc P[n,mc] * vf[mc][d]
    float2* rv = reinterpret_cast<float2*>(U);   // [40][32] @ byte 0
    {
        float ar[5], ai[5];
        #pragma unroll
        for (int j=0;j<5;j++){ ar[j]=0.f; ai[j]=0.f; }
        for (int mc=0; mc<40; mc++){
            float2 v = vf[mc*33+d];
            #pragma unroll
            for (int j=0;j<5;j++){
                float s = Smat[(g*5+j)*40 + mc];
                ar[j] += s*v.x; ai[j] += s*v.y;
            }
        }
        #pragma unroll
        for (int j=0;j<5;j++) rv[(g*5+j)*32 + d] = make_float2(ar[j], ai[j]);
    }
    // iFFT (ortho, numpy irfftn semantics), two-stage, split over u-halves
    float2* Tc2 = reinterpret_cast<float2*>(U + 2560);  // 8192 B over dead Smat
    float xacc[8];
    #pragma unroll
    for (int c=0;c<8;c++) xacc[c]=0.f;
    float wur = 1.f, wui = 0.f;                 // e^{+2pi i u g/8}, advanced over u
    float crr = csl[g], srr = snl[g];
    for (int half=0; half<2; half++){
        __syncthreads();
        {   // stage 1: Tc2[u][c][d] = sum_v wv * G[u,v,d] * e^{+2pi i v c/8}
            int u = half*4 + (g&3);
            int cbase = (g>>2)*4;
            #pragma unroll
            for (int cc=0; cc<4; cc++){
                int c = cbase + cc;
                float stepr = csl[c], stepi = snl[c];
                float wr=1.f, wi=0.f, ar=0.f, ai=0.f;
                #pragma unroll
                for (int v=0; v<5; v++){
                    float2 Gv = rv[(u*5+v)*32 + d];
                    float wv = (v>=1 && v<=3)? 2.f : 1.f;
                    float gx = Gv.x*wv, gy = Gv.y*wv;
                    ar += gx*wr - gy*wi;
                    ai += gx*wi + gy*wr;
                    float nr = wr*stepr - wi*stepi, ni = wr*stepi + wi*stepr;
                    wr=nr; wi=ni;
                }
                Tc2[((u&3)*8 + c)*32 + d] = make_float2(ar, ai);
            }
        }
        __syncthreads();
        {   // stage 2: x[r=g][c][d] += Re{ Tc2[u][c][d] * e^{+2pi i u g/8} }
            #pragma unroll
            for (int uu=0; uu<4; uu++){
                float wrc = wur, wic = wui;
                #pragma unroll
                for (int c=0;c<8;c++){
                    float2 t = Tc2[(uu*8 + c)*32 + d];
                    xacc[c] += t.x*wrc - t.y*wic;
                }
                float nr = wur*crr - wui*srr, ni = wur*srr + wui*crr;
                wur=nr; wui=ni;
            }
        }
    }
    #pragma unroll
    for (int c=0;c<8;c++){
        size_t idx = ((size_t)win*64 + g*8 + c)*192 + h*32 + d;
        Bbuf[idx] += 0.125f*xacc[c];
    }
}

// ---------------- K4: proj (MFMA, pipelined) + window reverse + unshift + residual -> X1
__global__ __launch_bounds__(256,2) void k_proj(const float* __restrict__ Bbuf,
        const float* __restrict__ x, const __bf16* __restrict__ Wpt,
        const float* __restrict__ proj_b, float* __restrict__ X1){
    __shared__ __align__(16) __bf16 xt[64*200];
    __shared__ __align__(16) __bf16 Wt[192*72];
    int tid = threadIdx.x;
    int win = blockIdx.x;
    {   // stage A tile: Bbuf f32 -> bf16 LDS, vectorized
        int tok = tid>>2, part = tid&3;
        const float* srcp = Bbuf + ((size_t)win*64 + tok)*192 + part*48;
        #pragma unroll
        for (int i8=0;i8<6;i8++){
            float4 a4 = *reinterpret_cast<const float4*>(srcp + i8*8);
            float4 b4 = *reinterpret_cast<const float4*>(srcp + i8*8 + 4);
            bf16x8 pk;
            pk[0]=(__bf16)a4.x; pk[1]=(__bf16)a4.y; pk[2]=(__bf16)a4.z; pk[3]=(__bf16)a4.w;
            pk[4]=(__bf16)b4.x; pk[5]=(__bf16)b4.y; pk[6]=(__bf16)b4.z; pk[7]=(__bf16)b4.w;
            *reinterpret_cast<bf16x8*>(&xt[tok*200 + part*48 + i8*8]) = pk;
        }
    }
    int lane = tid&63, w = tid>>6, lr = lane&15, lg = lane>>4;
    ushort8 wreg[6];
    auto ldW = [&](int kc, ushort8* wr){
        #pragma unroll
        for (int i=0;i<6;i++){
            int e = tid + i*256;
            int j = e>>3, k8 = e&7;
            wr[i] = *reinterpret_cast<const ushort8*>(
                reinterpret_cast<const unsigned short*>(Wpt) + (size_t)j*192 + kc*64 + k8*8);
        }
    };
    auto stW = [&](ushort8* wr){
        #pragma unroll
        for (int i=0;i<6;i++){
            int e = tid + i*256;
            int j = e>>3, k8 = e&7;
            *reinterpret_cast<ushort8*>(reinterpret_cast<unsigned short*>(Wt) + j*72 + k8*8) = wr[i];
        }
    };
    ldW(0, wreg);
    __syncthreads();
    stW(wreg);
    __syncthreads();
    f32x4 acc[4][3];
    #pragma unroll
    for (int m=0;m<4;m++)
        #pragma unroll
        for (int n=0;n<3;n++) acc[m][n] = (f32x4){0.f,0.f,0.f,0.f};
    for (int kc=0; kc<3; kc++){
        if (kc<2) ldW(kc+1, wreg);
        #pragma unroll
        for (int kk=0; kk<2; kk++){
            int ko = kc*64 + kk*32 + lg*8;
            bf16x8 a[4];
            #pragma unroll
            for (int m=0;m<4;m++) a[m] = ldfrag(&xt[(16*m+lr)*200 + ko]);
            int klo = kk*32 + lg*8;
            bf16x8 bfr[3];
            #pragma unroll
            for (int n=0;n<3;n++) bfr[n] = ldfrag(&Wt[(48*w+16*n+lr)*72 + klo]);
            #pragma unroll
            for (int m=0;m<4;m++)
                #pragma unroll
                for (int n=0;n<3;n++) acc[m][n] = MFMA16(a[m], bfr[n], acc[m][n]);
        }
        __syncthreads();
        if (kc<2) stW(wreg);
        __syncthreads();
    }
    int bb = win>>8, rem = win&255, wh = rem>>4, wwi = rem&15;
    #pragma unroll
    for (int m=0;m<4;m++)
        #pragma unroll
        for (int r=0;r<4;r++){
            int t = 16*m + 4*lg + r;
            int p = wh*8 + (t>>3), q = wwi*8 + (t&7);
            int hh = (p+SSH)&127, w2 = (q+SSH)&127;
            size_t pixb = (((size_t)bb*128 + hh)*128 + w2)*192;
            #pragma unroll
            for (int n=0;n<3;n++){
                int col = 48*w + 16*n + lr;
                X1[pixb + col] = acc[m][n][r] + proj_b[col] + x[pixb + col];
            }
        }
}

// ---------------- K5: LN2 + fc1(MFMA) + GELU + fc2(MFMA) + residual, pipelined
__global__ __launch_bounds__(256,2) void k_mlp(const float* __restrict__ X1,
        const float* __restrict__ g2, const float* __restrict__ b2v,
        const __bf16* __restrict__ W1t, const float* __restrict__ fc1b,
        const __bf16* __restrict__ W2t, const float* __restrict__ fc2b,
        float* __restrict__ out){
    __shared__ __align__(16) __bf16 xln[64*200];
    __shared__ __align__(16) __bf16 hbuf[64*200];
    __shared__ __align__(16) __bf16 Wt[192*72];
    int tid = threadIdx.x;
    size_t base = (size_t)blockIdx.x*64;
    {   // LN2, vectorized pack
        int tok = tid>>2, part = tid&3;
        const float* srcp = X1 + (base + tok)*192 + part*48;
        float v[48];
        #pragma unroll
        for (int i=0;i<12;i++){
            float4 t4 = *reinterpret_cast<const float4*>(srcp + i*4);
            v[i*4]=t4.x; v[i*4+1]=t4.y; v[i*4+2]=t4.z; v[i*4+3]=t4.w;
        }
        float s=0.f, ss=0.f;
        #pragma unroll
        for (int i=0;i<48;i++){ s+=v[i]; ss+=v[i]*v[i]; }
        s  += __shfl_xor(s,1);  s  += __shfl_xor(s,2);
        ss += __shfl_xor(ss,1); ss += __shfl_xor(ss,2);
        float mean = s*(1.f/192.f);
        float rstd = rsqrtf(ss*(1.f/192.f) - mean*mean + 1e-5f);
        #pragma unroll
        for (int i8=0;i8<6;i8++){
            bf16x8 pk;
            #pragma unroll
            for (int j=0;j<8;j++){
                int ch = part*48 + i8*8 + j;
                pk[j] = (__bf16)((v[i8*8+j]-mean)*rstd*g2[ch] + b2v[ch]);
            }
            *reinterpret_cast<bf16x8*>(&xln[tok*200 + part*48 + i8*8]) = pk;
        }
    }
    int lane = tid&63, w = tid>>6, lr = lane&15, lg = lane>>4;
    ushort8 wreg[6];
    // stage s in 0..23: hc = s/6, inner = s%6, fc1 if inner<3, kc = inner%3
    auto ldW = [&](int s, ushort8* wr){
        int hc = s/6, inner = s - hc*6;
        int kc = (inner<3)? inner : inner-3;
        const unsigned short* src;
        size_t rowstride;
        size_t off;
        if (inner<3){ src = reinterpret_cast<const unsigned short*>(W1t);
                      rowstride = 192; off = (size_t)(hc*192)*192 + kc*64; }
        else        { src = reinterpret_cast<const unsigned short*>(W2t);
                      rowstride = 768; off = (size_t)hc*192 + kc*64; }
        #pragma unroll
        for (int i=0;i<6;i++){
            int e = tid + i*256;
            int j = e>>3, k8 = e&7;
            wr[i] = *reinterpret_cast<const ushort8*>(src + (size_t)j*rowstride + off + k8*8);
        }
    };
    auto stW = [&](ushort8* wr){
        #pragma unroll
        for (int i=0;i<6;i++){
            int e = tid + i*256;
            int j = e>>3, k8 = e&7;
            *reinterpret_cast<ushort8*>(reinterpret_cast<unsigned short*>(Wt) + j*72 + k8*8) = wr[i];
        }
    };
    ldW(0, wreg);
    __syncthreads();
    stW(wreg);
    __syncthreads();
    f32x4 acc1[4][3], acc2[4][3];
    #pragma unroll
    for (int m=0;m<4;m++)
        #pragma unroll
        for (int n=0;n<3;n++){ acc1[m][n] = (f32x4){0.f,0.f,0.f,0.f};
                               acc2[m][n] = (f32x4){0.f,0.f,0.f,0.f}; }
    for (int s=0; s<24; s++){
        int hc = s/6, inner = s - hc*6;
        bool fc1 = inner<3;
        int kc = fc1 ? inner : inner-3;
        if (s<23) ldW(s+1, wreg);
        const __bf16* A = fc1 ? xln : hbuf;
        #pragma unroll
        for (int kk=0; kk<2; kk++){
            int ko = kc*64 + kk*32 + lg*8;
            bf16x8 a[4];
            #pragma unroll
            for (int m=0;m<4;m++) a[m] = ldfrag(&A[(16*m+lr)*200 + ko]);
            int klo = kk*32 + lg*8;
            bf16x8 bfr[3];
            #pragma unroll
            for (int n=0;n<3;n++) bfr[n] = ldfrag(&Wt[(48*w+16*n+lr)*72 + klo]);
            if (fc1){
                #pragma unroll
                for (int m=0;m<4;m++)
                    #pragma unroll
                    for (int n=0;n<3;n++) acc1[m][n] = MFMA16(a[m], bfr[n], acc1[m][n]);
            } else {
                #pragma unroll
                for (int m=0;m<4;m++)
                    #pragma unroll
                    for (int n=0;n<3;n++) acc2[m][n] = MFMA16(a[m], bfr[n], acc2[m][n]);
            }
        }
        if (inner==2){
            // fc1 chunk complete: bias + exact GELU -> hbuf, reset acc1
            #pragma unroll
            for (int n=0;n<3;n++){
                int jcol = 48*w + 16*n + lr;
                float b1 = fc1b[hc*192 + jcol];
                #pragma unroll
                for (int m=0;m<4;m++)
                    #pragma unroll
                    for (int r=0;r<4;r++){
                        float xv = acc1[m][n][r] + b1;
                        float gv = 0.5f*xv*(1.f + erff(xv*0.70710678118654752f));
                        hbuf[(16*m + 4*lg + r)*200 + jcol] = (__bf16)gv;
                        acc1[m][n][r] = 0.f;
                    }
            }
        }
        __syncthreads();
        if (s<23) stW(wreg);
        __syncthreads();
    }
    #pragma unroll
    for (int n=0;n<3;n++){
        int col = 48*w + 16*n + lr;
        float b2 = fc2b[col];
        #pragma unroll
        for (int m=0;m<4;m++)
            #pragma unroll
            for (int r=0;r<4;r++){
                size_t t = base + 16*m + 4*lg + r;
                out[t*192 + col] = acc2[m][n][r] + b2 + X1[t*192 + col];
            }
    }
}

extern "C" void kernel_launch(void* const* d_in, const int* in_sizes, int n_in,
                              void* d_out, int out_size, void* d_ws, size_t ws_size,
                              hipStream_t stream) {
    const float* x     = (const float*)d_in[0];
    const float* mask  = (const float*)d_in[1];
    const float* n1g   = (const float*)d_in[2];
    const float* n1b   = (const float*)d_in[3];
    const float* qkvw  = (const float*)d_in[4];
    const float* qkvb  = (const float*)d_in[5];
    const float* relt  = (const float*)d_in[6];
    const float* projw = (const float*)d_in[7];
    const float* projb = (const float*)d_in[8];
    const float* n2g   = (const float*)d_in[9];
    const float* n2b   = (const float*)d_in[10];
    const float* fc1w  = (const float*)d_in[11];
    const float* fc1b  = (const float*)d_in[12];
    const float* fc2w  = (const float*)d_in[13];
    const float* fc2b  = (const float*)d_in[14];
    float* out = (float*)d_out;

    char* wsb = (char*)d_ws;
    __bf16* Sb  = (__bf16*)wsb;                        // 150,994,944 B
    float*  X1  = (float*)(wsb + 150994944);           // 100,663,296 B
    __bf16* Wqt = (__bf16*)(wsb + 251658240);          //    221,184 B
    __bf16* Wpt = (__bf16*)(wsb + 251879424);          //     73,728 B
    __bf16* W1t = (__bf16*)(wsb + 251953152);          //    294,912 B
    __bf16* W2t = (__bf16*)(wsb + 252248064);          //    294,912 B

    k_prep   <<<576,   256, 0, stream>>>(qkvw, projw, fc1w, fc2w, Wqt, Wpt, W1t, W2t);
    k_qkv    <<<2048,  256, 0, stream>>>(x, n1g, n1b, Wqt, qkvb, Sb);
    k_spatial<<<2048,  256, 0, stream>>>(Sb, relt, mask, out);
    k_fattn  <<<12288, 256, 0, stream>>>(Sb, qkvb, out);
    k_proj   <<<2048,  256, 0, stream>>>(out, x, Wpt, projb, X1);
    k_mlp    <<<2048,  256, 0, stream>>>(X1, n2g, n2b, W1t, fc1b, W2t, fc2b, out);
}

// Round 7
// 922.333 us; speedup vs baseline: 4.0176x; 1.2837x over previous
//
#include <hip/hip_runtime.h>
#include <hip/hip_bf16.h>
#include <math.h>

#define SSH 4
#define SCALE 0.17677669529663687f  // 1/sqrt(32)

typedef __bf16 bf16x8 __attribute__((ext_vector_type(8)));
typedef __bf16 bf16x4 __attribute__((ext_vector_type(4)));
typedef unsigned short ushort8 __attribute__((ext_vector_type(8)));
typedef float  f32x4  __attribute__((ext_vector_type(4)));

static __device__ __forceinline__ f32x4 mfma16(bf16x8 a, bf16x8 b, f32x4 c){
    return __builtin_amdgcn_mfma_f32_16x16x32_bf16(a, b, c, 0, 0, 0);
}
#define MFMA16(a,b,c) mfma16((a),(b),(c))

static __device__ __forceinline__ bf16x8 ldfrag(const __bf16* p){
    return *reinterpret_cast<const bf16x8*>(p);
}
static __device__ __forceinline__ f32x4 zero4(){
    f32x4 z; z[0]=0.f; z[1]=0.f; z[2]=0.f; z[3]=0.f; return z;
}

// ---------------- K0: weight prep (bf16 [N][K]) + Fourier constant tables ----
__global__ __launch_bounds__(256) void k_prep(const float* __restrict__ qkvw,
        const float* __restrict__ projw, const float* __restrict__ fc1w,
        const float* __restrict__ fc2w, __bf16* __restrict__ Wq,
        __bf16* __restrict__ Wp, __bf16* __restrict__ W1, __bf16* __restrict__ W2,
        __bf16* __restrict__ Fre, __bf16* __restrict__ Fim,
        __bf16* __restrict__ Ci,  __bf16* __restrict__ nSi){
    int i = blockIdx.x*256 + threadIdx.x;
    if (i < 110592){ int n = i/192, k = i - n*192; Wq[i] = (__bf16)qkvw[k*576 + n]; }
    if (i < 36864) { int n = i/192, k = i - n*192; Wp[i] = (__bf16)projw[k*192 + n]; }
    if (i < 147456){ int n = i/192, k = i - n*192; W1[i] = (__bf16)fc1w[k*768 + n]; }
    if (i < 147456){ int n = i/768, k = i - n*768; W2[i] = (__bf16)fc2w[k*192 + n]; }
    // forward DFT table F[n][p], n = u*5+v (40 rows, pad 48 w/ zero), p = r*8+c
    if (i < 3072){
        int n = i>>6, p = i&63;
        float vr = 0.f, vi = 0.f;
        if (n < 40){
            int u = n/5, v = n - u*5, r = p>>3, c = p&7;
            int k = (u*r + v*c)&7;
            float ang = (float)k * 0.78539816339744831f;
            vr = cosf(ang)*0.125f; vi = -sinf(ang)*0.125f;
        }
        Fre[i] = (__bf16)vr; Fim[i] = (__bf16)vi;
    }
    // inverse table Ci[p][n] = wv*cos/8, nSi[p][n] = -wv*sin/8 (cols n>=40 zero)
    if (i < 4096){
        int p = i>>6, n = i&63;
        float vc = 0.f, vs = 0.f;
        if (n < 40){
            int u = n/5, v = n - u*5, r = p>>3, c = p&7;
            int k = (u*r + v*c)&7;
            float ang = (float)k * 0.78539816339744831f;
            float wv = (v>=1 && v<=3)? 2.f : 1.f;
            vc = wv*cosf(ang)*0.125f; vs = -wv*sinf(ang)*0.125f;
        }
        Ci[i] = (__bf16)vc; nSi[i] = (__bf16)vs;
    }
}

// ---------------- K1: LN1 + shift + window partition + qkv GEMM (MFMA, pipelined)
__global__ __launch_bounds__(256,2) void k_qkv(const float* __restrict__ x,
        const float* __restrict__ n1g, const float* __restrict__ n1b,
        const __bf16* __restrict__ Wqt, const float* __restrict__ qkv_b,
        __bf16* __restrict__ S){
    __shared__ __align__(16) __bf16 xw[64*200];
    __shared__ __align__(16) __bf16 Wt[192*72];
    int tid = threadIdx.x;
    int win = blockIdx.x;
    int bb = win>>8, rem = win&255, wh = rem>>4, wwi = rem&15;
    {
        int tok = tid>>2, part = tid&3;
        int r = tok>>3, c = tok&7;
        int sh = (wh*8 + r + SSH)&127, sw = (wwi*8 + c + SSH)&127;
        const float* srcp = x + (((size_t)(bb*128+sh))*128 + sw)*192 + part*48;
        float v[48];
        #pragma unroll
        for (int i=0;i<12;i++){
            float4 t4 = *reinterpret_cast<const float4*>(srcp + i*4);
            v[i*4]=t4.x; v[i*4+1]=t4.y; v[i*4+2]=t4.z; v[i*4+3]=t4.w;
        }
        float s=0.f, ss=0.f;
        #pragma unroll
        for (int i=0;i<48;i++){ s+=v[i]; ss+=v[i]*v[i]; }
        s  += __shfl_xor(s,1);  s  += __shfl_xor(s,2);
        ss += __shfl_xor(ss,1); ss += __shfl_xor(ss,2);
        float mean = s*(1.f/192.f);
        float rstd = rsqrtf(ss*(1.f/192.f) - mean*mean + 1e-5f);
        #pragma unroll
        for (int i8=0;i8<6;i8++){
            bf16x8 pk;
            #pragma unroll
            for (int j=0;j<8;j++){
                int ch = part*48 + i8*8 + j;
                pk[j] = (__bf16)((v[i8*8+j]-mean)*rstd*n1g[ch] + n1b[ch]);
            }
            *reinterpret_cast<bf16x8*>(&xw[tok*200 + part*48 + i8*8]) = pk;
        }
    }
    int lane = tid&63, w = tid>>6, lr = lane&15, lg = lane>>4;
    ushort8 wreg[6];
    auto ldW = [&](int s, ushort8* wr){
        int nc = s/3, kc = s - nc*3;
        #pragma unroll
        for (int i=0;i<6;i++){
            int e = tid + i*256;
            int j = e>>3, k8 = e&7;
            wr[i] = *reinterpret_cast<const ushort8*>(
                reinterpret_cast<const unsigned short*>(Wqt) + (size_t)(nc*192+j)*192 + kc*64 + k8*8);
        }
    };
    auto stW = [&](ushort8* wr){
        #pragma unroll
        for (int i=0;i<6;i++){
            int e = tid + i*256;
            int j = e>>3, k8 = e&7;
            *reinterpret_cast<ushort8*>(reinterpret_cast<unsigned short*>(Wt) + j*72 + k8*8) = wr[i];
        }
    };
    ldW(0, wreg);
    __syncthreads();
    stW(wreg);
    __syncthreads();
    f32x4 acc[4][3];
    #pragma unroll
    for (int m=0;m<4;m++)
        #pragma unroll
        for (int n=0;n<3;n++) acc[m][n] = zero4();
    for (int s=0; s<9; s++){
        int nc = s/3, kc = s - nc*3;
        if (s<8) ldW(s+1, wreg);
        #pragma unroll
        for (int kk=0; kk<2; kk++){
            int ko = kc*64 + kk*32 + lg*8;
            bf16x8 a[4];
            #pragma unroll
            for (int m=0;m<4;m++) a[m] = ldfrag(&xw[(16*m+lr)*200 + ko]);
            int klo = kk*32 + lg*8;
            bf16x8 bfr[3];
            #pragma unroll
            for (int n=0;n<3;n++) bfr[n] = ldfrag(&Wt[(48*w+16*n+lr)*72 + klo]);
            #pragma unroll
            for (int m=0;m<4;m++)
                #pragma unroll
                for (int n=0;n<3;n++) acc[m][n] = MFMA16(a[m], bfr[n], acc[m][n]);
        }
        if (kc==2){
            #pragma unroll
            for (int n=0;n<3;n++){
                int col = nc*192 + 48*w + 16*n + lr;
                float bias = qkv_b[col];
                #pragma unroll
                for (int m=0;m<4;m++)
                    #pragma unroll
                    for (int r=0;r<4;r++){
                        int row = 16*m + 4*lg + r;
                        S[(size_t)(win*64+row)*576 + col] = (__bf16)(acc[m][n][r] + bias);
                    }
            }
            #pragma unroll
            for (int m=0;m<4;m++)
                #pragma unroll
                for (int n=0;n<3;n++) acc[m][n] = zero4();
        }
        __syncthreads();
        if (s<8) stW(wreg);
        __syncthreads();
    }
}

// ---------------- K2: spatial window attention from S -> Bbuf (d_out) --------
__global__ __launch_bounds__(256,3) void k_spatial(const __bf16* __restrict__ S,
        const float* __restrict__ relt, const float* __restrict__ mask,
        float* __restrict__ Bbuf){
    __shared__ __align__(16) float qs[64*36], ks[64*36], vs[64*36];
    __shared__ float Sc[64*66];
    int tid = threadIdx.x;
    int win = blockIdx.x;
    int widx = win & 255;
    int n_o = tid>>2;
    int d0  = (tid&3)*8;
    int c0  = (tid&3)*16;
    for (int h=0; h<6; h++){
        __syncthreads();
        #pragma unroll
        for (int i=0;i<24;i++){
            int e = tid + i*256;
            int m = e>>11, rem2 = e&2047, row = rem2>>5, d = rem2&31;
            float v = (float)S[((size_t)win*64+row)*576 + m*192 + h*32 + d];
            float* dst = (m==0)?qs:((m==1)?ks:vs);
            dst[row*36+d] = v;
        }
        __syncthreads();
        float qreg[32];
        #pragma unroll
        for (int i=0;i<8;i++){
            float4 q4 = *reinterpret_cast<const float4*>(&qs[n_o*36 + i*4]);
            qreg[i*4]=q4.x; qreg[i*4+1]=q4.y; qreg[i*4+2]=q4.z; qreg[i*4+3]=q4.w;
        }
        float sc[16];
        #pragma unroll
        for (int j=0;j<16;j++){
            int col = c0 + j;
            float dot = 0.f;
            #pragma unroll
            for (int i=0;i<8;i++){
                float4 k4 = *reinterpret_cast<const float4*>(&ks[col*36 + i*4]);
                dot += qreg[i*4]*k4.x + qreg[i*4+1]*k4.y + qreg[i*4+2]*k4.z + qreg[i*4+3]*k4.w;
            }
            int dr = (n_o>>3) - (col>>3) + 7;
            int dc = (n_o&7)  - (col&7)  + 7;
            float bias = relt[(dr*15 + dc)*6 + h];
            float mk   = mask[((widx*64 + n_o)<<6) + col];
            sc[j] = dot*SCALE + bias + mk;
        }
        float mx = sc[0];
        #pragma unroll
        for (int j=1;j<16;j++) mx = fmaxf(mx, sc[j]);
        mx = fmaxf(mx, __shfl_xor(mx,1));
        mx = fmaxf(mx, __shfl_xor(mx,2));
        float sum = 0.f;
        #pragma unroll
        for (int j=0;j<16;j++){ sc[j] = __expf(sc[j]-mx); sum += sc[j]; }
        sum += __shfl_xor(sum,1);
        sum += __shfl_xor(sum,2);
        float inv = 1.f/sum;
        #pragma unroll
        for (int j=0;j<16;j++) Sc[n_o*66 + c0 + j] = sc[j]*inv;
        __syncthreads();
        float oacc[8];
        #pragma unroll
        for (int j=0;j<8;j++) oacc[j]=0.f;
        for (int mcol=0; mcol<64; mcol++){
            float p = Sc[n_o*66 + mcol];
            float4 v0 = *reinterpret_cast<const float4*>(&vs[mcol*36 + d0]);
            float4 v1 = *reinterpret_cast<const float4*>(&vs[mcol*36 + d0 + 4]);
            oacc[0]+=p*v0.x; oacc[1]+=p*v0.y; oacc[2]+=p*v0.z; oacc[3]+=p*v0.w;
            oacc[4]+=p*v1.x; oacc[5]+=p*v1.y; oacc[6]+=p*v1.z; oacc[7]+=p*v1.w;
        }
        float* outp = Bbuf + ((size_t)win*64 + n_o)*192 + h*32 + d0;
        *reinterpret_cast<float4*>(outp)   = make_float4(oacc[0],oacc[1],oacc[2],oacc[3]);
        *reinterpret_cast<float4*>(outp+4) = make_float4(oacc[4],oacc[5],oacc[6],oacc[7]);
    }
}

// ------- K3: Fourier branch, fully MFMA. One block per (window, head). -------
// Layouts (all row-major for D[r][c] = sum_k A[r][k]*B[c][k]):
//   St[d][p] (32x88), Gq/Gk [n][d] (48x40), Gv^T [d][n] (32x88, cols48..63=0),
//   P [n][mc] (48x88), R^T [d][n] (32x88, cols48..63=0), Smat f32 [48][52].
__global__ __launch_bounds__(256,3) void k_fattn(const __bf16* __restrict__ S,
        const float* __restrict__ qkv_b,
        const __bf16* __restrict__ Fre_g, const __bf16* __restrict__ Fim_g,
        const __bf16* __restrict__ Ci_g,  const __bf16* __restrict__ nSi_g,
        float* __restrict__ Bbuf){
    __shared__ __align__(16) unsigned char arena[45056];
    __bf16* Gq_r = (__bf16*)(arena);             // [48][40]
    __bf16* Gqin = (__bf16*)(arena + 3840);      // [48][40] (negated Qi)
    __bf16* Gk_r = (__bf16*)(arena + 7680);      // [48][40]
    __bf16* Gk_i = (__bf16*)(arena + 11520);     // [48][40]
    __bf16* Rt_r = (__bf16*)(arena);             // [32][88] overlay (PV phase)
    __bf16* Rt_i = (__bf16*)(arena + 5632);      // [32][88]
    __bf16* Gv_r = (__bf16*)(arena + 15360);     // [32][88]
    __bf16* Gv_i = (__bf16*)(arena + 20992);     // [32][88]
    __bf16* St   = (__bf16*)(arena + 26624);     // [32][88] (spectra phase)
    float*  Smat = (float*) (arena + 26624);     // [48][52] overlay (QK phase)
    __bf16* P    = (__bf16*)(arena + 36608);     // [48][88]
    int tid = threadIdx.x;
    int win = blockIdx.x / 6, h = blockIdx.x - win*6;
    int lane = tid&63, w = tid>>6, lr = lane&15, lg = lane>>4;
    bf16x4 z4; z4[0]=z4[1]=z4[2]=z4[3]=(__bf16)0.f;
    {   // zero Gv^T pad cols 48..63 (K-padding for PV)
        int t2 = tid & 127;
        __bf16* A = (tid<128)? Gv_r : Gv_i;
        int row = t2>>2, c4 = (t2&3)*4;
        *reinterpret_cast<bf16x4*>(A + row*88 + 48 + c4) = z4;
    }
    const size_t sbase = (size_t)win*64*576 + h*32;
    // ---- spectra: for m in {q,k,v}: stage St = S_m^T, then GEMM vs F tables
    for (int m=0;m<3;m++){
        __syncthreads();
        {   // transpose-stage: St[d][p]
            int d = tid&31, pg = tid>>5;
            const __bf16* sp = S + sbase + (size_t)m*192 + (size_t)pg*8*576 + d;
            bf16x4 v0, v1;
            v0[0]=sp[0];      v0[1]=sp[576];    v0[2]=sp[1152];   v0[3]=sp[1728];
            v1[0]=sp[2304];   v1[1]=sp[2880];   v1[2]=sp[3456];   v1[3]=sp[4032];
            *reinterpret_cast<bf16x4*>(&St[d*88 + pg*8])     = v0;
            *reinterpret_cast<bf16x4*>(&St[d*88 + pg*8 + 4]) = v1;
        }
        __syncthreads();
        for (int j=w; j<12; j+=4){
            int term = j/6, r2 = j - term*6;
            if (m<2){
                // G[n][d] = F_term . St   (A=F rows n, B=St rows d)
                int mt = r2>>1, nt = r2&1;
                const __bf16* Ag = (term? Fim_g : Fre_g) + (16*mt+lr)*64 + lg*8;
                f32x4 acc = zero4();
                acc = MFMA16(*reinterpret_cast<const bf16x8*>(Ag),
                             ldfrag(&St[(16*nt+lr)*88 + lg*8]), acc);
                acc = MFMA16(*reinterpret_cast<const bf16x8*>(Ag+32),
                             ldfrag(&St[(16*nt+lr)*88 + 32 + lg*8]), acc);
                int d = 16*nt + lr;
                float b = qkv_b[m*192 + h*32 + d];
                __bf16* dst = (m==0)? (term? Gqin : Gq_r) : (term? Gk_i : Gk_r);
                #pragma unroll
                for (int r=0;r<4;r++){
                    int n = 16*mt + 4*lg + r;
                    float val = acc[r] + ((term==0) ? ((n==0)? -7.f*b : b) : b);
                    if (m==0 && term==1) val = -val;     // store -Qi
                    dst[n*40 + d] = (__bf16)val;
                }
            } else {
                // Gv^T[d][n] = St . F_term^T  (A=St rows d, B=F rows n)
                int mt = r2/3, nt = r2 - mt*3;
                const __bf16* Bg = (term? Fim_g : Fre_g) + (16*nt+lr)*64 + lg*8;
                f32x4 acc = zero4();
                acc = MFMA16(ldfrag(&St[(16*mt+lr)*88 + lg*8]),
                             *reinterpret_cast<const bf16x8*>(Bg), acc);
                acc = MFMA16(ldfrag(&St[(16*mt+lr)*88 + 32 + lg*8]),
                             *reinterpret_cast<const bf16x8*>(Bg+32), acc);
                int n = 16*nt + lr;
                __bf16* dst = term? Gv_i : Gv_r;
                #pragma unroll
                for (int r=0;r<4;r++){
                    int d = 16*mt + 4*lg + r;
                    float b = qkv_b[2*192 + h*32 + d];
                    float val = acc[r] + ((term==0) ? ((n==0)? -7.f*b : b) : b);
                    dst[d*88 + n] = (__bf16)val;
                }
            }
        }
    }
    __syncthreads();
    // ---- QK^T: S = Q.K^T complex; Smat = SCALE*|S|
    for (int j=w; j<9; j+=4){
        int mt = j/3, nt = j - mt*3;
        bf16x8 qr = ldfrag(&Gq_r[(16*mt+lr)*40 + lg*8]);
        bf16x8 qi = ldfrag(&Gqin[(16*mt+lr)*40 + lg*8]);
        bf16x8 kr = ldfrag(&Gk_r[(16*nt+lr)*40 + lg*8]);
        bf16x8 ki = ldfrag(&Gk_i[(16*nt+lr)*40 + lg*8]);
        f32x4 sre = MFMA16(qi, ki, zero4());   // (-Qi).Ki
        sre = MFMA16(qr, kr, sre);             // + Qr.Kr
        f32x4 t1 = MFMA16(qr, ki, zero4());    // Qr.Ki
        f32x4 t2 = MFMA16(qi, kr, zero4());    // (-Qi).Kr
        #pragma unroll
        for (int r=0;r<4;r++){
            float sim = t1[r] - t2[r];
            Smat[(16*mt + 4*lg + r)*52 + 16*nt + lr] =
                SCALE * sqrtf(sre[r]*sre[r] + sim*sim);
        }
    }
    __syncthreads();
    // ---- softmax rows 0..39 over cols 0..39 (in place in Smat)
    if (tid < 160){
        int row = tid>>2, part = tid&3, e0 = part*10;
        float mx = -1e30f;
        #pragma unroll
        for (int j=0;j<10;j++) mx = fmaxf(mx, Smat[row*52 + e0 + j]);
        mx = fmaxf(mx, __shfl_xor(mx,1));
        mx = fmaxf(mx, __shfl_xor(mx,2));
        float ex[10]; float sum=0.f;
        #pragma unroll
        for (int j=0;j<10;j++){ ex[j] = __expf(Smat[row*52+e0+j]-mx); sum += ex[j]; }
        sum += __shfl_xor(sum,1);
        sum += __shfl_xor(sum,2);
        float inv = 1.f/sum;
        #pragma unroll
        for (int j=0;j<10;j++) Smat[row*52+e0+j] = ex[j]*inv;
    }
    __syncthreads();
    // ---- P (bf16, zero-padded) + zero R^T pad cols
    for (int e=tid; e<3072; e+=256){
        int row = e>>6, col = e&63;
        float v = (row<40 && col<40)? Smat[row*52+col] : 0.f;
        P[row*88+col] = (__bf16)v;
    }
    {
        int t2 = tid & 127;
        __bf16* A = (tid<128)? Rt_r : Rt_i;
        int row = t2>>2, c4 = (t2&3)*4;
        *reinterpret_cast<bf16x4*>(A + row*88 + 48 + c4) = z4;
    }
    __syncthreads();
    // ---- PV: R^T[d][n] = Gv^T . P^T   (K = mc, padded to 64)
    for (int j=w; j<12; j+=4){
        int term = j/6, r2 = j - term*6;
        int dt = r2/3, nt = r2 - dt*3;
        const __bf16* Gv = term? Gv_i : Gv_r;
        f32x4 acc = zero4();
        #pragma unroll
        for (int ks=0; ks<2; ks++)
            acc = MFMA16(ldfrag(&Gv[(16*dt+lr)*88 + ks*32 + lg*8]),
                         ldfrag(&P [(16*nt+lr)*88 + ks*32 + lg*8]), acc);
        __bf16* dst = term? Rt_i : Rt_r;
        #pragma unroll
        for (int r=0;r<4;r++)
            dst[(16*dt + 4*lg + r)*88 + 16*nt + lr] = (__bf16)acc[r];
    }
    __syncthreads();
    // ---- iFFT: x[p][d] = Ci.R_r^T + nSi.R_i^T ; accumulate into Bbuf
    for (int j=w; j<8; j+=4){
        int dt = j>>2, pt = j&3;
        f32x4 acc = zero4();
        #pragma unroll
        for (int ks=0; ks<2; ks++)
            acc = MFMA16(*reinterpret_cast<const bf16x8*>(nSi_g + (16*pt+lr)*64 + ks*32 + lg*8),
                         ldfrag(&Rt_i[(16*dt+lr)*88 + ks*32 + lg*8]), acc);
        #pragma unroll
        for (int ks=0; ks<2; ks++)
            acc = MFMA16(*reinterpret_cast<const bf16x8*>(Ci_g + (16*pt+lr)*64 + ks*32 + lg*8),
                         ldfrag(&Rt_r[(16*dt+lr)*88 + ks*32 + lg*8]), acc);
        #pragma unroll
        for (int r=0;r<4;r++){
            int p = 16*pt + 4*lg + r, d = 16*dt + lr;
            size_t idx = ((size_t)win*64 + p)*192 + h*32 + d;
            Bbuf[idx] += acc[r];
        }
    }
}

// ---------------- K4: proj (MFMA, pipelined) + window reverse + unshift + residual -> X1
__global__ __launch_bounds__(256,2) void k_proj(const float* __restrict__ Bbuf,
        const float* __restrict__ x, const __bf16* __restrict__ Wpt,
        const float* __restrict__ proj_b, float* __restrict__ X1){
    __shared__ __align__(16) __bf16 xt[64*200];
    __shared__ __align__(16) __bf16 Wt[192*72];
    int tid = threadIdx.x;
    int win = blockIdx.x;
    {
        int tok = tid>>2, part = tid&3;
        const float* srcp = Bbuf + ((size_t)win*64 + tok)*192 + part*48;
        #pragma unroll
        for (int i8=0;i8<6;i8++){
            float4 a4 = *reinterpret_cast<const float4*>(srcp + i8*8);
            float4 b4 = *reinterpret_cast<const float4*>(srcp + i8*8 + 4);
            bf16x8 pk;
            pk[0]=(__bf16)a4.x; pk[1]=(__bf16)a4.y; pk[2]=(__bf16)a4.z; pk[3]=(__bf16)a4.w;
            pk[4]=(__bf16)b4.x; pk[5]=(__bf16)b4.y; pk[6]=(__bf16)b4.z; pk[7]=(__bf16)b4.w;
            *reinterpret_cast<bf16x8*>(&xt[tok*200 + part*48 + i8*8]) = pk;
        }
    }
    int lane = tid&63, w = tid>>6, lr = lane&15, lg = lane>>4;
    ushort8 wreg[6];
    auto ldW = [&](int kc, ushort8* wr){
        #pragma unroll
        for (int i=0;i<6;i++){
            int e = tid + i*256;
            int j = e>>3, k8 = e&7;
            wr[i] = *reinterpret_cast<const ushort8*>(
                reinterpret_cast<const unsigned short*>(Wpt) + (size_t)j*192 + kc*64 + k8*8);
        }
    };
    auto stW = [&](ushort8* wr){
        #pragma unroll
        for (int i=0;i<6;i++){
            int e = tid + i*256;
            int j = e>>3, k8 = e&7;
            *reinterpret_cast<ushort8*>(reinterpret_cast<unsigned short*>(Wt) + j*72 + k8*8) = wr[i];
        }
    };
    ldW(0, wreg);
    __syncthreads();
    stW(wreg);
    __syncthreads();
    f32x4 acc[4][3];
    #pragma unroll
    for (int m=0;m<4;m++)
        #pragma unroll
        for (int n=0;n<3;n++) acc[m][n] = zero4();
    for (int kc=0; kc<3; kc++){
        if (kc<2) ldW(kc+1, wreg);
        #pragma unroll
        for (int kk=0; kk<2; kk++){
            int ko = kc*64 + kk*32 + lg*8;
            bf16x8 a[4];
            #pragma unroll
            for (int m=0;m<4;m++) a[m] = ldfrag(&xt[(16*m+lr)*200 + ko]);
            int klo = kk*32 + lg*8;
            bf16x8 bfr[3];
            #pragma unroll
            for (int n=0;n<3;n++) bfr[n] = ldfrag(&Wt[(48*w+16*n+lr)*72 + klo]);
            #pragma unroll
            for (int m=0;m<4;m++)
                #pragma unroll
                for (int n=0;n<3;n++) acc[m][n] = MFMA16(a[m], bfr[n], acc[m][n]);
        }
        __syncthreads();
        if (kc<2) stW(wreg);
        __syncthreads();
    }
    int bb = win>>8, rem = win&255, wh = rem>>4, wwi = rem&15;
    #pragma unroll
    for (int m=0;m<4;m++)
        #pragma unroll
        for (int r=0;r<4;r++){
            int t = 16*m + 4*lg + r;
            int p = wh*8 + (t>>3), q = wwi*8 + (t&7);
            int hh = (p+SSH)&127, w2 = (q+SSH)&127;
            size_t pixb = (((size_t)bb*128 + hh)*128 + w2)*192;
            #pragma unroll
            for (int n=0;n<3;n++){
                int col = 48*w + 16*n + lr;
                X1[pixb + col] = acc[m][n][r] + proj_b[col] + x[pixb + col];
            }
        }
}

// ---------------- K5: LN2 + fc1(MFMA) + GELU + fc2(MFMA) + residual, pipelined
__global__ __launch_bounds__(256,2) void k_mlp(const float* __restrict__ X1,
        const float* __restrict__ g2, const float* __restrict__ b2v,
        const __bf16* __restrict__ W1t, const float* __restrict__ fc1b,
        const __bf16* __restrict__ W2t, const float* __restrict__ fc2b,
        float* __restrict__ out){
    __shared__ __align__(16) __bf16 xln[64*200];
    __shared__ __align__(16) __bf16 hbuf[64*200];
    __shared__ __align__(16) __bf16 Wt[192*72];
    int tid = threadIdx.x;
    size_t base = (size_t)blockIdx.x*64;
    {
        int tok = tid>>2, part = tid&3;
        const float* srcp = X1 + (base + tok)*192 + part*48;
        float v[48];
        #pragma unroll
        for (int i=0;i<12;i++){
            float4 t4 = *reinterpret_cast<const float4*>(srcp + i*4);
            v[i*4]=t4.x; v[i*4+1]=t4.y; v[i*4+2]=t4.z; v[i*4+3]=t4.w;
        }
        float s=0.f, ss=0.f;
        #pragma unroll
        for (int i=0;i<48;i++){ s+=v[i]; ss+=v[i]*v[i]; }
        s  += __shfl_xor(s,1);  s  += __shfl_xor(s,2);
        ss += __shfl_xor(ss,1); ss += __shfl_xor(ss,2);
        float mean = s*(1.f/192.f);
        float rstd = rsqrtf(ss*(1.f/192.f) - mean*mean + 1e-5f);
        #pragma unroll
        for (int i8=0;i8<6;i8++){
            bf16x8 pk;
            #pragma unroll
            for (int j=0;j<8;j++){
                int ch = part*48 + i8*8 + j;
                pk[j] = (__bf16)((v[i8*8+j]-mean)*rstd*g2[ch] + b2v[ch]);
            }
            *reinterpret_cast<bf16x8*>(&xln[tok*200 + part*48 + i8*8]) = pk;
        }
    }
    int lane = tid&63, w = tid>>6, lr = lane&15, lg = lane>>4;
    ushort8 wreg[6];
    auto ldW = [&](int s, ushort8* wr){
        int hc = s/6, inner = s - hc*6;
        int kc = (inner<3)? inner : inner-3;
        const unsigned short* src;
        size_t rowstride;
        size_t off;
        if (inner<3){ src = reinterpret_cast<const unsigned short*>(W1t);
                      rowstride = 192; off = (size_t)(hc*192)*192 + kc*64; }
        else        { src = reinterpret_cast<const unsigned short*>(W2t);
                      rowstride = 768; off = (size_t)hc*192 + kc*64; }
        #pragma unroll
        for (int i=0;i<6;i++){
            int e = tid + i*256;
            int j = e>>3, k8 = e&7;
            wr[i] = *reinterpret_cast<const ushort8*>(src + (size_t)j*rowstride + off + k8*8);
        }
    };
    auto stW = [&](ushort8* wr){
        #pragma unroll
        for (int i=0;i<6;i++){
            int e = tid + i*256;
            int j = e>>3, k8 = e&7;
            *reinterpret_cast<ushort8*>(reinterpret_cast<unsigned short*>(Wt) + j*72 + k8*8) = wr[i];
        }
    };
    ldW(0, wreg);
    __syncthreads();
    stW(wreg);
    __syncthreads();
    f32x4 acc1[4][3], acc2[4][3];
    #pragma unroll
    for (int m=0;m<4;m++)
        #pragma unroll
        for (int n=0;n<3;n++){ acc1[m][n] = zero4(); acc2[m][n] = zero4(); }
    for (int s=0; s<24; s++){
        int hc = s/6, inner = s - hc*6;
        bool fc1 = inner<3;
        int kc = fc1 ? inner : inner-3;
        if (s<23) ldW(s+1, wreg);
        const __bf16* A = fc1 ? xln : hbuf;
        #pragma unroll
        for (int kk=0; kk<2; kk++){
            int ko = kc*64 + kk*32 + lg*8;
            bf16x8 a[4];
            #pragma unroll
            for (int m=0;m<4;m++) a[m] = ldfrag(&A[(16*m+lr)*200 + ko]);
            int klo = kk*32 + lg*8;
            bf16x8 bfr[3];
            #pragma unroll
            for (int n=0;n<3;n++) bfr[n] = ldfrag(&Wt[(48*w+16*n+lr)*72 + klo]);
            if (fc1){
                #pragma unroll
                for (int m=0;m<4;m++)
                    #pragma unroll
                    for (int n=0;n<3;n++) acc1[m][n] = MFMA16(a[m], bfr[n], acc1[m][n]);
            } else {
                #pragma unroll
                for (int m=0;m<4;m++)
                    #pragma unroll
                    for (int n=0;n<3;n++) acc2[m][n] = MFMA16(a[m], bfr[n], acc2[m][n]);
            }
        }
        if (inner==2){
            #pragma unroll
            for (int n=0;n<3;n++){
                int jcol = 48*w + 16*n + lr;
                float b1 = fc1b[hc*192 + jcol];
                #pragma unroll
                for (int m=0;m<4;m++)
                    #pragma unroll
                    for (int r=0;r<4;r++){
                        float xv = acc1[m][n][r] + b1;
                        float gv = 0.5f*xv*(1.f + erff(xv*0.70710678118654752f));
                        hbuf[(16*m + 4*lg + r)*200 + jcol] = (__bf16)gv;
                        acc1[m][n][r] = 0.f;
                    }
            }
        }
        __syncthreads();
        if (s<23) stW(wreg);
        __syncthreads();
    }
    #pragma unroll
    for (int n=0;n<3;n++){
        int col = 48*w + 16*n + lr;
        float b2 = fc2b[col];
        #pragma unroll
        for (int m=0;m<4;m++)
            #pragma unroll
            for (int r=0;r<4;r++){
                size_t t = base + 16*m + 4*lg + r;
                out[t*192 + col] = acc2[m][n][r] + b2 + X1[t*192 + col];
            }
    }
}

extern "C" void kernel_launch(void* const* d_in, const int* in_sizes, int n_in,
                              void* d_out, int out_size, void* d_ws, size_t ws_size,
                              hipStream_t stream) {
    const float* x     = (const float*)d_in[0];
    const float* mask  = (const float*)d_in[1];
    const float* n1g   = (const float*)d_in[2];
    const float* n1b   = (const float*)d_in[3];
    const float* qkvw  = (const float*)d_in[4];
    const float* qkvb  = (const float*)d_in[5];
    const float* relt  = (const float*)d_in[6];
    const float* projw = (const float*)d_in[7];
    const float* projb = (const float*)d_in[8];
    const float* n2g   = (const float*)d_in[9];
    const float* n2b   = (const float*)d_in[10];
    const float* fc1w  = (const float*)d_in[11];
    const float* fc1b  = (const float*)d_in[12];
    const float* fc2w  = (const float*)d_in[13];
    const float* fc2b  = (const float*)d_in[14];
    float* out = (float*)d_out;

    char* wsb = (char*)d_ws;
    __bf16* Sb  = (__bf16*)wsb;                        // 150,994,944 B
    float*  X1  = (float*)(wsb + 150994944);           // 100,663,296 B
    __bf16* Wqt = (__bf16*)(wsb + 251658240);          //    221,184 B
    __bf16* Wpt = (__bf16*)(wsb + 251879424);          //     73,728 B
    __bf16* W1t = (__bf16*)(wsb + 251953152);          //    294,912 B
    __bf16* W2t = (__bf16*)(wsb + 252248064);          //    294,912 B
    __bf16* Fre = (__bf16*)(wsb + 252542976);          //      6,144 B
    __bf16* Fim = (__bf16*)(wsb + 252549120);          //      6,144 B
    __bf16* Ci  = (__bf16*)(wsb + 252555264);          //      8,192 B
    __bf16* nSi = (__bf16*)(wsb + 252563456);          //      8,192 B

    k_prep   <<<576,   256, 0, stream>>>(qkvw, projw, fc1w, fc2w, Wqt, Wpt, W1t, W2t,
                                         Fre, Fim, Ci, nSi);
    k_qkv    <<<2048,  256, 0, stream>>>(x, n1g, n1b, Wqt, qkvb, Sb);
    k_spatial<<<2048,  256, 0, stream>>>(Sb, relt, mask, out);
    k_fattn  <<<12288, 256, 0, stream>>>(Sb, qkvb, Fre, Fim, Ci, nSi, out);
    k_proj   <<<2048,  256, 0, stream>>>(out, x, Wpt, projb, X1);
    k_mlp    <<<2048,  256, 0, stream>>>(X1, n2g, n2b, W1t, fc1b, W2t, fc2b, out);
}

// Round 8
// 621.498 us; speedup vs baseline: 5.9622x; 1.4840x over previous
//
#include <hip/hip_runtime.h>
#include <hip/hip_bf16.h>
#include <math.h>

#define SSH 4
#define SCALE 0.17677669529663687f  // 1/sqrt(32)

typedef __bf16 bf16x8 __attribute__((ext_vector_type(8)));
typedef __bf16 bf16x4 __attribute__((ext_vector_type(4)));
typedef unsigned short ushort8 __attribute__((ext_vector_type(8)));
typedef float  f32x4  __attribute__((ext_vector_type(4)));

static __device__ __forceinline__ f32x4 mfma16(bf16x8 a, bf16x8 b, f32x4 c){
    return __builtin_amdgcn_mfma_f32_16x16x32_bf16(a, b, c, 0, 0, 0);
}
#define MFMA16(a,b,c) mfma16((a),(b),(c))

static __device__ __forceinline__ bf16x8 ldfrag(const __bf16* p){
    return *reinterpret_cast<const bf16x8*>(p);
}
static __device__ __forceinline__ f32x4 zero4(){
    f32x4 z; z[0]=0.f; z[1]=0.f; z[2]=0.f; z[3]=0.f; return z;
}

// ---------------- K0: weight prep (bf16 [N][K]) + Fourier constant tables ----
__global__ __launch_bounds__(256) void k_prep(const float* __restrict__ qkvw,
        const float* __restrict__ projw, const float* __restrict__ fc1w,
        const float* __restrict__ fc2w, __bf16* __restrict__ Wq,
        __bf16* __restrict__ Wp, __bf16* __restrict__ W1, __bf16* __restrict__ W2,
        __bf16* __restrict__ Fre, __bf16* __restrict__ Fim,
        __bf16* __restrict__ Ci,  __bf16* __restrict__ nSi){
    int i = blockIdx.x*256 + threadIdx.x;
    if (i < 110592){ int n = i/192, k = i - n*192; Wq[i] = (__bf16)qkvw[k*576 + n]; }
    if (i < 36864) { int n = i/192, k = i - n*192; Wp[i] = (__bf16)projw[k*192 + n]; }
    if (i < 147456){ int n = i/192, k = i - n*192; W1[i] = (__bf16)fc1w[k*768 + n]; }
    if (i < 147456){ int n = i/768, k = i - n*768; W2[i] = (__bf16)fc2w[k*192 + n]; }
    // forward DFT table F[n][p], n = u*5+v (40 rows, pad 48 w/ zero), p = r*8+c
    if (i < 3072){
        int n = i>>6, p = i&63;
        float vr = 0.f, vi = 0.f;
        if (n < 40){
            int u = n/5, v = n - u*5, r = p>>3, c = p&7;
            int k = (u*r + v*c)&7;
            float ang = (float)k * 0.78539816339744831f;
            vr = cosf(ang)*0.125f; vi = -sinf(ang)*0.125f;
        }
        Fre[i] = (__bf16)vr; Fim[i] = (__bf16)vi;
    }
    // inverse table Ci[p][n] = wv*cos/8, nSi[p][n] = -wv*sin/8 (cols n>=40 zero)
    if (i < 4096){
        int p = i>>6, n = i&63;
        float vc = 0.f, vs = 0.f;
        if (n < 40){
            int u = n/5, v = n - u*5, r = p>>3, c = p&7;
            int k = (u*r + v*c)&7;
            float ang = (float)k * 0.78539816339744831f;
            float wv = (v>=1 && v<=3)? 2.f : 1.f;
            vc = wv*cosf(ang)*0.125f; vs = -wv*sinf(ang)*0.125f;
        }
        Ci[i] = (__bf16)vc; nSi[i] = (__bf16)vs;
    }
}

// ---------------- K1: LN1 + shift + window partition + qkv GEMM (MFMA, pipelined)
__global__ __launch_bounds__(256,2) void k_qkv(const float* __restrict__ x,
        const float* __restrict__ n1g, const float* __restrict__ n1b,
        const __bf16* __restrict__ Wqt, const float* __restrict__ qkv_b,
        __bf16* __restrict__ S){
    __shared__ __align__(16) __bf16 xw[64*200];
    __shared__ __align__(16) __bf16 Wt[192*72];
    int tid = threadIdx.x;
    int win = blockIdx.x;
    int bb = win>>8, rem = win&255, wh = rem>>4, wwi = rem&15;
    {
        int tok = tid>>2, part = tid&3;
        int r = tok>>3, c = tok&7;
        int sh = (wh*8 + r + SSH)&127, sw = (wwi*8 + c + SSH)&127;
        const float* srcp = x + (((size_t)(bb*128+sh))*128 + sw)*192 + part*48;
        float v[48];
        #pragma unroll
        for (int i=0;i<12;i++){
            float4 t4 = *reinterpret_cast<const float4*>(srcp + i*4);
            v[i*4]=t4.x; v[i*4+1]=t4.y; v[i*4+2]=t4.z; v[i*4+3]=t4.w;
        }
        float s=0.f, ss=0.f;
        #pragma unroll
        for (int i=0;i<48;i++){ s+=v[i]; ss+=v[i]*v[i]; }
        s  += __shfl_xor(s,1);  s  += __shfl_xor(s,2);
        ss += __shfl_xor(ss,1); ss += __shfl_xor(ss,2);
        float mean = s*(1.f/192.f);
        float rstd = rsqrtf(ss*(1.f/192.f) - mean*mean + 1e-5f);
        #pragma unroll
        for (int i8=0;i8<6;i8++){
            bf16x8 pk;
            #pragma unroll
            for (int j=0;j<8;j++){
                int ch = part*48 + i8*8 + j;
                pk[j] = (__bf16)((v[i8*8+j]-mean)*rstd*n1g[ch] + n1b[ch]);
            }
            *reinterpret_cast<bf16x8*>(&xw[tok*200 + part*48 + i8*8]) = pk;
        }
    }
    int lane = tid&63, w = tid>>6, lr = lane&15, lg = lane>>4;
    ushort8 wreg[6];
    auto ldW = [&](int s, ushort8* wr){
        int nc = s/3, kc = s - nc*3;
        #pragma unroll
        for (int i=0;i<6;i++){
            int e = tid + i*256;
            int j = e>>3, k8 = e&7;
            wr[i] = *reinterpret_cast<const ushort8*>(
                reinterpret_cast<const unsigned short*>(Wqt) + (size_t)(nc*192+j)*192 + kc*64 + k8*8);
        }
    };
    auto stW = [&](ushort8* wr){
        #pragma unroll
        for (int i=0;i<6;i++){
            int e = tid + i*256;
            int j = e>>3, k8 = e&7;
            *reinterpret_cast<ushort8*>(reinterpret_cast<unsigned short*>(Wt) + j*72 + k8*8) = wr[i];
        }
    };
    ldW(0, wreg);
    __syncthreads();
    stW(wreg);
    __syncthreads();
    f32x4 acc[4][3];
    #pragma unroll
    for (int m=0;m<4;m++)
        #pragma unroll
        for (int n=0;n<3;n++) acc[m][n] = zero4();
    for (int s=0; s<9; s++){
        int nc = s/3, kc = s - nc*3;
        if (s<8) ldW(s+1, wreg);
        #pragma unroll
        for (int kk=0; kk<2; kk++){
            int ko = kc*64 + kk*32 + lg*8;
            bf16x8 a[4];
            #pragma unroll
            for (int m=0;m<4;m++) a[m] = ldfrag(&xw[(16*m+lr)*200 + ko]);
            int klo = kk*32 + lg*8;
            bf16x8 bfr[3];
            #pragma unroll
            for (int n=0;n<3;n++) bfr[n] = ldfrag(&Wt[(48*w+16*n+lr)*72 + klo]);
            #pragma unroll
            for (int m=0;m<4;m++)
                #pragma unroll
                for (int n=0;n<3;n++) acc[m][n] = MFMA16(a[m], bfr[n], acc[m][n]);
        }
        if (kc==2){
            #pragma unroll
            for (int n=0;n<3;n++){
                int col = nc*192 + 48*w + 16*n + lr;
                float bias = qkv_b[col];
                #pragma unroll
                for (int m=0;m<4;m++)
                    #pragma unroll
                    for (int r=0;r<4;r++){
                        int row = 16*m + 4*lg + r;
                        S[(size_t)(win*64+row)*576 + col] = (__bf16)(acc[m][n][r] + bias);
                    }
            }
            #pragma unroll
            for (int m=0;m<4;m++)
                #pragma unroll
                for (int n=0;n<3;n++) acc[m][n] = zero4();
        }
        __syncthreads();
        if (s<8) stW(wreg);
        __syncthreads();
    }
}

// ---------------- K2: spatial window attention (MFMA) from S -> Bbuf (d_out) --
// per (window): 6 heads serial. Q/K fragments read DIRECT from global S.
// wave w owns output rows 16w..16w+15; softmax fully in-register (shfl over lr).
__global__ __launch_bounds__(256,4) void k_spatial(const __bf16* __restrict__ S,
        const float* __restrict__ relt, const float* __restrict__ mask,
        float* __restrict__ Bbuf){
    __shared__ __align__(16) __bf16 P[64*72];    // 9216 B (wave-private row blocks)
    __shared__ __align__(16) __bf16 Vt[32*72];   // 4608 B (V transposed [d][mc])
    __shared__ float reltL[1350];                // rel-bias table [225][6]
    int tid = threadIdx.x;
    int win = blockIdx.x;
    int widx = win & 255;
    int lane = tid&63, w = tid>>6, lr = lane&15, lg = lane>>4;
    for (int e=tid; e<1350; e+=256) reltL[e] = relt[e];
    // per-lane constants: mask (head-invariant) + rel-bias index, 16 acc elements
    float mreg[16];
    int bidx[16];
    #pragma unroll
    for (int nt=0; nt<4; nt++)
        #pragma unroll
        for (int r=0;r<4;r++){
            int row = 16*w + 4*lg + r;
            int col = 16*nt + lr;
            mreg[nt*4+r] = mask[((widx*64 + row)<<6) + col];
            int dr = (row>>3)-(col>>3)+7, dc = (row&7)-(col&7)+7;
            bidx[nt*4+r] = (dr*15+dc)*6;
        }
    const size_t sbase = (size_t)win*64*576;
    const __bf16* Sq = S + sbase;
    const __bf16* Sk = S + sbase + 192;
    const __bf16* Sv = S + sbase + 384;
    for (int h=0; h<6; h++){
        __syncthreads();     // protect Vt against previous head's PV reads
        {   // stage Vt[d][p] (transpose of V)
            int d = tid&31, pg = tid>>5;
            const __bf16* sp = Sv + (size_t)(pg*8)*576 + h*32 + d;
            bf16x4 v0, v1;
            v0[0]=sp[0];    v0[1]=sp[576];  v0[2]=sp[1152]; v0[3]=sp[1728];
            v1[0]=sp[2304]; v1[1]=sp[2880]; v1[2]=sp[3456]; v1[3]=sp[4032];
            *reinterpret_cast<bf16x4*>(&Vt[d*72 + pg*8])   = v0;
            *reinterpret_cast<bf16x4*>(&Vt[d*72 + pg*8+4]) = v1;
        }
        __syncthreads();
        // QK^T: 4 tiles per wave, K=32 (one MFMA each), operands direct-global
        bf16x8 aq = ldfrag(Sq + (size_t)(16*w+lr)*576 + h*32 + lg*8);
        f32x4 acc[4];
        #pragma unroll
        for (int nt=0;nt<4;nt++){
            bf16x8 bk = ldfrag(Sk + (size_t)(16*nt+lr)*576 + h*32 + lg*8);
            acc[nt] = MFMA16(aq, bk, zero4());
        }
        // scores + in-wave softmax (4 independent rows per lane-group)
        float p[16];
        #pragma unroll
        for (int r=0;r<4;r++){
            float sc[4];
            #pragma unroll
            for (int nt=0;nt<4;nt++)
                sc[nt] = acc[nt][r]*SCALE + reltL[bidx[nt*4+r] + h] + mreg[nt*4+r];
            float mx = fmaxf(fmaxf(sc[0],sc[1]),fmaxf(sc[2],sc[3]));
            mx = fmaxf(mx, __shfl_xor(mx,1));
            mx = fmaxf(mx, __shfl_xor(mx,2));
            mx = fmaxf(mx, __shfl_xor(mx,4));
            mx = fmaxf(mx, __shfl_xor(mx,8));
            float sum = 0.f;
            #pragma unroll
            for (int nt=0;nt<4;nt++){ sc[nt] = __expf(sc[nt]-mx); sum += sc[nt]; }
            sum += __shfl_xor(sum,1);
            sum += __shfl_xor(sum,2);
            sum += __shfl_xor(sum,4);
            sum += __shfl_xor(sum,8);
            float inv = 1.f/sum;
            #pragma unroll
            for (int nt=0;nt<4;nt++) p[r*4+nt] = sc[nt]*inv;
        }
        // P rows (wave-private: written and read only by wave w)
        #pragma unroll
        for (int r=0;r<4;r++)
            #pragma unroll
            for (int nt=0;nt<4;nt++)
                P[(16*w + 4*lg + r)*72 + 16*nt + lr] = (__bf16)p[r*4+nt];
        // PV: out[n][d] = P . V, K=64 (2 MFMA), 2 d-tiles
        #pragma unroll
        for (int dt=0; dt<2; dt++){
            f32x4 o = zero4();
            #pragma unroll
            for (int ks=0; ks<2; ks++)
                o = MFMA16(ldfrag(&P[(16*w+lr)*72 + ks*32 + lg*8]),
                           ldfrag(&Vt[(16*dt+lr)*72 + ks*32 + lg*8]), o);
            #pragma unroll
            for (int r=0;r<4;r++){
                int row = 16*w + 4*lg + r;
                Bbuf[((size_t)win*64 + row)*192 + h*32 + 16*dt + lr] = o[r];
            }
        }
    }
}

// ------- K3: Fourier branch, fully MFMA. One block per (window, head). -------
__global__ __launch_bounds__(256,3) void k_fattn(const __bf16* __restrict__ S,
        const float* __restrict__ qkv_b,
        const __bf16* __restrict__ Fre_g, const __bf16* __restrict__ Fim_g,
        const __bf16* __restrict__ Ci_g,  const __bf16* __restrict__ nSi_g,
        float* __restrict__ Bbuf){
    __shared__ __align__(16) unsigned char arena[45056];
    __bf16* Gq_r = (__bf16*)(arena);             // [48][40]
    __bf16* Gqin = (__bf16*)(arena + 3840);      // [48][40] (negated Qi)
    __bf16* Gk_r = (__bf16*)(arena + 7680);      // [48][40]
    __bf16* Gk_i = (__bf16*)(arena + 11520);     // [48][40]
    __bf16* Rt_r = (__bf16*)(arena);             // [32][88] overlay (PV phase)
    __bf16* Rt_i = (__bf16*)(arena + 5632);      // [32][88]
    __bf16* Gv_r = (__bf16*)(arena + 15360);     // [32][88]
    __bf16* Gv_i = (__bf16*)(arena + 20992);     // [32][88]
    __bf16* St   = (__bf16*)(arena + 26624);     // [32][88] (spectra phase)
    float*  Smat = (float*) (arena + 26624);     // [48][52] overlay (QK phase)
    __bf16* P    = (__bf16*)(arena + 36608);     // [48][88]
    int tid = threadIdx.x;
    int win = blockIdx.x / 6, h = blockIdx.x - win*6;
    int lane = tid&63, w = tid>>6, lr = lane&15, lg = lane>>4;
    bf16x4 z4; z4[0]=z4[1]=z4[2]=z4[3]=(__bf16)0.f;
    {   // zero Gv^T pad cols 48..63 (K-padding for PV)
        int t2 = tid & 127;
        __bf16* A = (tid<128)? Gv_r : Gv_i;
        int row = t2>>2, c4 = (t2&3)*4;
        *reinterpret_cast<bf16x4*>(A + row*88 + 48 + c4) = z4;
    }
    const size_t sbase = (size_t)win*64*576 + h*32;
    // ---- spectra: for m in {q,k,v}: stage St = S_m^T, then GEMM vs F tables
    for (int m=0;m<3;m++){
        __syncthreads();
        {   // transpose-stage: St[d][p]
            int d = tid&31, pg = tid>>5;
            const __bf16* sp = S + sbase + (size_t)m*192 + (size_t)pg*8*576 + d;
            bf16x4 v0, v1;
            v0[0]=sp[0];      v0[1]=sp[576];    v0[2]=sp[1152];   v0[3]=sp[1728];
            v1[0]=sp[2304];   v1[1]=sp[2880];   v1[2]=sp[3456];   v1[3]=sp[4032];
            *reinterpret_cast<bf16x4*>(&St[d*88 + pg*8])     = v0;
            *reinterpret_cast<bf16x4*>(&St[d*88 + pg*8 + 4]) = v1;
        }
        __syncthreads();
        for (int j=w; j<12; j+=4){
            int term = j/6, r2 = j - term*6;
            if (m<2){
                int mt = r2>>1, nt = r2&1;
                const __bf16* Ag = (term? Fim_g : Fre_g) + (16*mt+lr)*64 + lg*8;
                f32x4 acc = zero4();
                acc = MFMA16(*reinterpret_cast<const bf16x8*>(Ag),
                             ldfrag(&St[(16*nt+lr)*88 + lg*8]), acc);
                acc = MFMA16(*reinterpret_cast<const bf16x8*>(Ag+32),
                             ldfrag(&St[(16*nt+lr)*88 + 32 + lg*8]), acc);
                int d = 16*nt + lr;
                float b = qkv_b[m*192 + h*32 + d];
                __bf16* dst = (m==0)? (term? Gqin : Gq_r) : (term? Gk_i : Gk_r);
                #pragma unroll
                for (int r=0;r<4;r++){
                    int n = 16*mt + 4*lg + r;
                    float val = acc[r] + ((term==0) ? ((n==0)? -7.f*b : b) : b);
                    if (m==0 && term==1) val = -val;     // store -Qi
                    dst[n*40 + d] = (__bf16)val;
                }
            } else {
                int mt = r2/3, nt = r2 - mt*3;
                const __bf16* Bg = (term? Fim_g : Fre_g) + (16*nt+lr)*64 + lg*8;
                f32x4 acc = zero4();
                acc = MFMA16(ldfrag(&St[(16*mt+lr)*88 + lg*8]),
                             *reinterpret_cast<const bf16x8*>(Bg), acc);
                acc = MFMA16(ldfrag(&St[(16*mt+lr)*88 + 32 + lg*8]),
                             *reinterpret_cast<const bf16x8*>(Bg+32), acc);
                int n = 16*nt + lr;
                __bf16* dst = term? Gv_i : Gv_r;
                #pragma unroll
                for (int r=0;r<4;r++){
                    int d = 16*mt + 4*lg + r;
                    float b = qkv_b[2*192 + h*32 + d];
                    float val = acc[r] + ((term==0) ? ((n==0)? -7.f*b : b) : b);
                    dst[d*88 + n] = (__bf16)val;
                }
            }
        }
    }
    __syncthreads();
    // ---- QK^T: S = Q.K^T complex; Smat = SCALE*|S|
    for (int j=w; j<9; j+=4){
        int mt = j/3, nt = j - mt*3;
        bf16x8 qr = ldfrag(&Gq_r[(16*mt+lr)*40 + lg*8]);
        bf16x8 qi = ldfrag(&Gqin[(16*mt+lr)*40 + lg*8]);
        bf16x8 kr = ldfrag(&Gk_r[(16*nt+lr)*40 + lg*8]);
        bf16x8 ki = ldfrag(&Gk_i[(16*nt+lr)*40 + lg*8]);
        f32x4 sre = MFMA16(qi, ki, zero4());   // (-Qi).Ki
        sre = MFMA16(qr, kr, sre);             // + Qr.Kr
        f32x4 t1 = MFMA16(qr, ki, zero4());    // Qr.Ki
        f32x4 t2 = MFMA16(qi, kr, zero4());    // (-Qi).Kr
        #pragma unroll
        for (int r=0;r<4;r++){
            float sim = t1[r] - t2[r];
            Smat[(16*mt + 4*lg + r)*52 + 16*nt + lr] =
                SCALE * sqrtf(sre[r]*sre[r] + sim*sim);
        }
    }
    __syncthreads();
    // ---- softmax rows 0..39 over cols 0..39 (in place in Smat)
    if (tid < 160){
        int row = tid>>2, part = tid&3, e0 = part*10;
        float mx = -1e30f;
        #pragma unroll
        for (int j=0;j<10;j++) mx = fmaxf(mx, Smat[row*52 + e0 + j]);
        mx = fmaxf(mx, __shfl_xor(mx,1));
        mx = fmaxf(mx, __shfl_xor(mx,2));
        float ex[10]; float sum=0.f;
        #pragma unroll
        for (int j=0;j<10;j++){ ex[j] = __expf(Smat[row*52+e0+j]-mx); sum += ex[j]; }
        sum += __shfl_xor(sum,1);
        sum += __shfl_xor(sum,2);
        float inv = 1.f/sum;
        #pragma unroll
        for (int j=0;j<10;j++) Smat[row*52+e0+j] = ex[j]*inv;
    }
    __syncthreads();
    // ---- P (bf16, zero-padded) + zero R^T pad cols
    for (int e=tid; e<3072; e+=256){
        int row = e>>6, col = e&63;
        float v = (row<40 && col<40)? Smat[row*52+col] : 0.f;
        P[row*88+col] = (__bf16)v;
    }
    {
        int t2 = tid & 127;
        __bf16* A = (tid<128)? Rt_r : Rt_i;
        int row = t2>>2, c4 = (t2&3)*4;
        *reinterpret_cast<bf16x4*>(A + row*88 + 48 + c4) = z4;
    }
    __syncthreads();
    // ---- PV: R^T[d][n] = Gv^T . P^T   (K = mc, padded to 64)
    for (int j=w; j<12; j+=4){
        int term = j/6, r2 = j - term*6;
        int dt = r2/3, nt = r2 - dt*3;
        const __bf16* Gv = term? Gv_i : Gv_r;
        f32x4 acc = zero4();
        #pragma unroll
        for (int ks=0; ks<2; ks++)
            acc = MFMA16(ldfrag(&Gv[(16*dt+lr)*88 + ks*32 + lg*8]),
                         ldfrag(&P [(16*nt+lr)*88 + ks*32 + lg*8]), acc);
        __bf16* dst = term? Rt_i : Rt_r;
        #pragma unroll
        for (int r=0;r<4;r++)
            dst[(16*dt + 4*lg + r)*88 + 16*nt + lr] = (__bf16)acc[r];
    }
    __syncthreads();
    // ---- iFFT: x[p][d] = Ci.R_r^T + nSi.R_i^T ; accumulate into Bbuf
    for (int j=w; j<8; j+=4){
        int dt = j>>2, pt = j&3;
        f32x4 acc = zero4();
        #pragma unroll
        for (int ks=0; ks<2; ks++)
            acc = MFMA16(*reinterpret_cast<const bf16x8*>(nSi_g + (16*pt+lr)*64 + ks*32 + lg*8),
                         ldfrag(&Rt_i[(16*dt+lr)*88 + ks*32 + lg*8]), acc);
        #pragma unroll
        for (int ks=0; ks<2; ks++)
            acc = MFMA16(*reinterpret_cast<const bf16x8*>(Ci_g + (16*pt+lr)*64 + ks*32 + lg*8),
                         ldfrag(&Rt_r[(16*dt+lr)*88 + ks*32 + lg*8]), acc);
        #pragma unroll
        for (int r=0;r<4;r++){
            int p = 16*pt + 4*lg + r, d = 16*dt + lr;
            size_t idx = ((size_t)win*64 + p)*192 + h*32 + d;
            Bbuf[idx] += acc[r];
        }
    }
}

// ---------------- K4: proj (MFMA, pipelined) + window reverse + unshift + residual -> X1
__global__ __launch_bounds__(256,2) void k_proj(const float* __restrict__ Bbuf,
        const float* __restrict__ x, const __bf16* __restrict__ Wpt,
        const float* __restrict__ proj_b, float* __restrict__ X1){
    __shared__ __align__(16) __bf16 xt[64*200];
    __shared__ __align__(16) __bf16 Wt[192*72];
    int tid = threadIdx.x;
    int win = blockIdx.x;
    {
        int tok = tid>>2, part = tid&3;
        const float* srcp = Bbuf + ((size_t)win*64 + tok)*192 + part*48;
        #pragma unroll
        for (int i8=0;i8<6;i8++){
            float4 a4 = *reinterpret_cast<const float4*>(srcp + i8*8);
            float4 b4 = *reinterpret_cast<const float4*>(srcp + i8*8 + 4);
            bf16x8 pk;
            pk[0]=(__bf16)a4.x; pk[1]=(__bf16)a4.y; pk[2]=(__bf16)a4.z; pk[3]=(__bf16)a4.w;
            pk[4]=(__bf16)b4.x; pk[5]=(__bf16)b4.y; pk[6]=(__bf16)b4.z; pk[7]=(__bf16)b4.w;
            *reinterpret_cast<bf16x8*>(&xt[tok*200 + part*48 + i8*8]) = pk;
        }
    }
    int lane = tid&63, w = tid>>6, lr = lane&15, lg = lane>>4;
    ushort8 wreg[6];
    auto ldW = [&](int kc, ushort8* wr){
        #pragma unroll
        for (int i=0;i<6;i++){
            int e = tid + i*256;
            int j = e>>3, k8 = e&7;
            wr[i] = *reinterpret_cast<const ushort8*>(
                reinterpret_cast<const unsigned short*>(Wpt) + (size_t)j*192 + kc*64 + k8*8);
        }
    };
    auto stW = [&](ushort8* wr){
        #pragma unroll
        for (int i=0;i<6;i++){
            int e = tid + i*256;
            int j = e>>3, k8 = e&7;
            *reinterpret_cast<ushort8*>(reinterpret_cast<unsigned short*>(Wt) + j*72 + k8*8) = wr[i];
        }
    };
    ldW(0, wreg);
    __syncthreads();
    stW(wreg);
    __syncthreads();
    f32x4 acc[4][3];
    #pragma unroll
    for (int m=0;m<4;m++)
        #pragma unroll
        for (int n=0;n<3;n++) acc[m][n] = zero4();
    for (int kc=0; kc<3; kc++){
        if (kc<2) ldW(kc+1, wreg);
        #pragma unroll
        for (int kk=0; kk<2; kk++){
            int ko = kc*64 + kk*32 + lg*8;
            bf16x8 a[4];
            #pragma unroll
            for (int m=0;m<4;m++) a[m] = ldfrag(&xt[(16*m+lr)*200 + ko]);
            int klo = kk*32 + lg*8;
            bf16x8 bfr[3];
            #pragma unroll
            for (int n=0;n<3;n++) bfr[n] = ldfrag(&Wt[(48*w+16*n+lr)*72 + klo]);
            #pragma unroll
            for (int m=0;m<4;m++)
                #pragma unroll
                for (int n=0;n<3;n++) acc[m][n] = MFMA16(a[m], bfr[n], acc[m][n]);
        }
        __syncthreads();
        if (kc<2) stW(wreg);
        __syncthreads();
    }
    int bb = win>>8, rem = win&255, wh = rem>>4, wwi = rem&15;
    #pragma unroll
    for (int m=0;m<4;m++)
        #pragma unroll
        for (int r=0;r<4;r++){
            int t = 16*m + 4*lg + r;
            int p = wh*8 + (t>>3), q = wwi*8 + (t&7);
            int hh = (p+SSH)&127, w2 = (q+SSH)&127;
            size_t pixb = (((size_t)bb*128 + hh)*128 + w2)*192;
            #pragma unroll
            for (int n=0;n<3;n++){
                int col = 48*w + 16*n + lr;
                X1[pixb + col] = acc[m][n][r] + proj_b[col] + x[pixb + col];
            }
        }
}

// ---------------- K5: LN2 + fc1(MFMA) + GELU + fc2(MFMA) + residual, pipelined
__global__ __launch_bounds__(256,2) void k_mlp(const float* __restrict__ X1,
        const float* __restrict__ g2, const float* __restrict__ b2v,
        const __bf16* __restrict__ W1t, const float* __restrict__ fc1b,
        const __bf16* __restrict__ W2t, const float* __restrict__ fc2b,
        float* __restrict__ out){
    __shared__ __align__(16) __bf16 xln[64*200];
    __shared__ __align__(16) __bf16 hbuf[64*200];
    __shared__ __align__(16) __bf16 Wt[192*72];
    int tid = threadIdx.x;
    size_t base = (size_t)blockIdx.x*64;
    {
        int tok = tid>>2, part = tid&3;
        const float* srcp = X1 + (base + tok)*192 + part*48;
        float v[48];
        #pragma unroll
        for (int i=0;i<12;i++){
            float4 t4 = *reinterpret_cast<const float4*>(srcp + i*4);
            v[i*4]=t4.x; v[i*4+1]=t4.y; v[i*4+2]=t4.z; v[i*4+3]=t4.w;
        }
        float s=0.f, ss=0.f;
        #pragma unroll
        for (int i=0;i<48;i++){ s+=v[i]; ss+=v[i]*v[i]; }
        s  += __shfl_xor(s,1);  s  += __shfl_xor(s,2);
        ss += __shfl_xor(ss,1); ss += __shfl_xor(ss,2);
        float mean = s*(1.f/192.f);
        float rstd = rsqrtf(ss*(1.f/192.f) - mean*mean + 1e-5f);
        #pragma unroll
        for (int i8=0;i8<6;i8++){
            bf16x8 pk;
            #pragma unroll
            for (int j=0;j<8;j++){
                int ch = part*48 + i8*8 + j;
                pk[j] = (__bf16)((v[i8*8+j]-mean)*rstd*g2[ch] + b2v[ch]);
            }
            *reinterpret_cast<bf16x8*>(&xln[tok*200 + part*48 + i8*8]) = pk;
        }
    }
    int lane = tid&63, w = tid>>6, lr = lane&15, lg = lane>>4;
    ushort8 wreg[6];
    auto ldW = [&](int s, ushort8* wr){
        int hc = s/6, inner = s - hc*6;
        int kc = (inner<3)? inner : inner-3;
        const unsigned short* src;
        size_t rowstride;
        size_t off;
        if (inner<3){ src = reinterpret_cast<const unsigned short*>(W1t);
                      rowstride = 192; off = (size_t)(hc*192)*192 + kc*64; }
        else        { src = reinterpret_cast<const unsigned short*>(W2t);
                      rowstride = 768; off = (size_t)hc*192 + kc*64; }
        #pragma unroll
        for (int i=0;i<6;i++){
            int e = tid + i*256;
            int j = e>>3, k8 = e&7;
            wr[i] = *reinterpret_cast<const ushort8*>(src + (size_t)j*rowstride + off + k8*8);
        }
    };
    auto stW = [&](ushort8* wr){
        #pragma unroll
        for (int i=0;i<6;i++){
            int e = tid + i*256;
            int j = e>>3, k8 = e&7;
            *reinterpret_cast<ushort8*>(reinterpret_cast<unsigned short*>(Wt) + j*72 + k8*8) = wr[i];
        }
    };
    ldW(0, wreg);
    __syncthreads();
    stW(wreg);
    __syncthreads();
    f32x4 acc1[4][3], acc2[4][3];
    #pragma unroll
    for (int m=0;m<4;m++)
        #pragma unroll
        for (int n=0;n<3;n++){ acc1[m][n] = zero4(); acc2[m][n] = zero4(); }
    for (int s=0; s<24; s++){
        int hc = s/6, inner = s - hc*6;
        bool fc1 = inner<3;
        int kc = fc1 ? inner : inner-3;
        if (s<23) ldW(s+1, wreg);
        const __bf16* A = fc1 ? xln : hbuf;
        #pragma unroll
        for (int kk=0; kk<2; kk++){
            int ko = kc*64 + kk*32 + lg*8;
            bf16x8 a[4];
            #pragma unroll
            for (int m=0;m<4;m++) a[m] = ldfrag(&A[(16*m+lr)*200 + ko]);
            int klo = kk*32 + lg*8;
            bf16x8 bfr[3];
            #pragma unroll
            for (int n=0;n<3;n++) bfr[n] = ldfrag(&Wt[(48*w+16*n+lr)*72 + klo]);
            if (fc1){
                #pragma unroll
                for (int m=0;m<4;m++)
                    #pragma unroll
                    for (int n=0;n<3;n++) acc1[m][n] = MFMA16(a[m], bfr[n], acc1[m][n]);
            } else {
                #pragma unroll
                for (int m=0;m<4;m++)
                    #pragma unroll
                    for (int n=0;n<3;n++) acc2[m][n] = MFMA16(a[m], bfr[n], acc2[m][n]);
            }
        }
        if (inner==2){
            #pragma unroll
            for (int n=0;n<3;n++){
                int jcol = 48*w + 16*n + lr;
                float b1 = fc1b[hc*192 + jcol];
                #pragma unroll
                for (int m=0;m<4;m++)
                    #pragma unroll
                    for (int r=0;r<4;r++){
                        float xv = acc1[m][n][r] + b1;
                        float gv = 0.5f*xv*(1.f + erff(xv*0.70710678118654752f));
                        hbuf[(16*m + 4*lg + r)*200 + jcol] = (__bf16)gv;
                        acc1[m][n][r] = 0.f;
                    }
            }
        }
        __syncthreads();
        if (s<23) stW(wreg);
        __syncthreads();
    }
    #pragma unroll
    for (int n=0;n<3;n++){
        int col = 48*w + 16*n + lr;
        float b2 = fc2b[col];
        #pragma unroll
        for (int m=0;m<4;m++)
            #pragma unroll
            for (int r=0;r<4;r++){
                size_t t = base + 16*m + 4*lg + r;
                out[t*192 + col] = acc2[m][n][r] + b2 + X1[t*192 + col];
            }
    }
}

extern "C" void kernel_launch(void* const* d_in, const int* in_sizes, int n_in,
                              void* d_out, int out_size, void* d_ws, size_t ws_size,
                              hipStream_t stream) {
    const float* x     = (const float*)d_in[0];
    const float* mask  = (const float*)d_in[1];
    const float* n1g   = (const float*)d_in[2];
    const float* n1b   = (const float*)d_in[3];
    const float* qkvw  = (const float*)d_in[4];
    const float* qkvb  = (const float*)d_in[5];
    const float* relt  = (const float*)d_in[6];
    const float* projw = (const float*)d_in[7];
    const float* projb = (const float*)d_in[8];
    const float* n2g   = (const float*)d_in[9];
    const float* n2b   = (const float*)d_in[10];
    const float* fc1w  = (const float*)d_in[11];
    const float* fc1b  = (const float*)d_in[12];
    const float* fc2w  = (const float*)d_in[13];
    const float* fc2b  = (const float*)d_in[14];
    float* out = (float*)d_out;

    char* wsb = (char*)d_ws;
    __bf16* Sb  = (__bf16*)wsb;                        // 150,994,944 B
    float*  X1  = (float*)(wsb + 150994944);           // 100,663,296 B
    __bf16* Wqt = (__bf16*)(wsb + 251658240);          //    221,184 B
    __bf16* Wpt = (__bf16*)(wsb + 251879424);          //     73,728 B
    __bf16* W1t = (__bf16*)(wsb + 251953152);          //    294,912 B
    __bf16* W2t = (__bf16*)(wsb + 252248064);          //    294,912 B
    __bf16* Fre = (__bf16*)(wsb + 252542976);          //      6,144 B
    __bf16* Fim = (__bf16*)(wsb + 252549120);          //      6,144 B
    __bf16* Ci  = (__bf16*)(wsb + 252555264);          //      8,192 B
    __bf16* nSi = (__bf16*)(wsb + 252563456);          //      8,192 B

    k_prep   <<<576,   256, 0, stream>>>(qkvw, projw, fc1w, fc2w, Wqt, Wpt, W1t, W2t,
                                         Fre, Fim, Ci, nSi);
    k_qkv    <<<2048,  256, 0, stream>>>(x, n1g, n1b, Wqt, qkvb, Sb);
    k_spatial<<<2048,  256, 0, stream>>>(Sb, relt, mask, out);
    k_fattn  <<<12288, 256, 0, stream>>>(Sb, qkvb, Fre, Fim, Ci, nSi, out);
    k_proj   <<<2048,  256, 0, stream>>>(out, x, Wpt, projb, X1);
    k_mlp    <<<2048,  256, 0, stream>>>(X1, n2g, n2b, W1t, fc1b, W2t, fc2b, out);
}

// Round 9
// 616.850 us; speedup vs baseline: 6.0072x; 1.0075x over previous
//
#include <hip/hip_runtime.h>
#include <hip/hip_bf16.h>
#include <math.h>

#define SSH 4
#define SCALE 0.17677669529663687f  // 1/sqrt(32)

typedef __bf16 bf16x8 __attribute__((ext_vector_type(8)));
typedef __bf16 bf16x4 __attribute__((ext_vector_type(4)));
typedef unsigned short ushort8 __attribute__((ext_vector_type(8)));
typedef float  f32x4  __attribute__((ext_vector_type(4)));

static __device__ __forceinline__ f32x4 mfma16(bf16x8 a, bf16x8 b, f32x4 c){
    return __builtin_amdgcn_mfma_f32_16x16x32_bf16(a, b, c, 0, 0, 0);
}
#define MFMA16(a,b,c) mfma16((a),(b),(c))

static __device__ __forceinline__ bf16x8 ldfrag(const __bf16* p){
    return *reinterpret_cast<const bf16x8*>(p);
}
static __device__ __forceinline__ f32x4 zero4(){
    f32x4 z; z[0]=0.f; z[1]=0.f; z[2]=0.f; z[3]=0.f; return z;
}
// tanh-form GELU via sigmoid identity: 0.5x(1+tanh(u)) == x * sigma(2u)
static __device__ __forceinline__ float gelu_fast(float x){
    float u = x*(0.7978845608f + 0.0356774081f*x*x);
    return __fdividef(x, 1.f + __expf(-2.f*u));
}

// ---------------- K0: weight prep (bf16 [N][K]) + Fourier constant tables ----
__global__ __launch_bounds__(256) void k_prep(const float* __restrict__ qkvw,
        const float* __restrict__ projw, const float* __restrict__ fc1w,
        const float* __restrict__ fc2w, __bf16* __restrict__ Wq,
        __bf16* __restrict__ Wp, __bf16* __restrict__ W1, __bf16* __restrict__ W2,
        __bf16* __restrict__ Fre, __bf16* __restrict__ Fim,
        __bf16* __restrict__ Ci,  __bf16* __restrict__ nSi){
    int i = blockIdx.x*256 + threadIdx.x;
    if (i < 110592){ int n = i/192, k = i - n*192; Wq[i] = (__bf16)qkvw[k*576 + n]; }
    if (i < 36864) { int n = i/192, k = i - n*192; Wp[i] = (__bf16)projw[k*192 + n]; }
    if (i < 147456){ int n = i/192, k = i - n*192; W1[i] = (__bf16)fc1w[k*768 + n]; }
    if (i < 147456){ int n = i/768, k = i - n*768; W2[i] = (__bf16)fc2w[k*192 + n]; }
    // forward DFT table F[n][p], n = u*5+v (40 rows, pad 48 w/ zero), p = r*8+c
    if (i < 3072){
        int n = i>>6, p = i&63;
        float vr = 0.f, vi = 0.f;
        if (n < 40){
            int u = n/5, v = n - u*5, r = p>>3, c = p&7;
            int k = (u*r + v*c)&7;
            float ang = (float)k * 0.78539816339744831f;
            vr = cosf(ang)*0.125f; vi = -sinf(ang)*0.125f;
        }
        Fre[i] = (__bf16)vr; Fim[i] = (__bf16)vi;
    }
    // inverse table Ci[p][n] = wv*cos/8, nSi[p][n] = -wv*sin/8 (cols n>=40 zero)
    if (i < 4096){
        int p = i>>6, n = i&63;
        float vc = 0.f, vs = 0.f;
        if (n < 40){
            int u = n/5, v = n - u*5, r = p>>3, c = p&7;
            int k = (u*r + v*c)&7;
            float ang = (float)k * 0.78539816339744831f;
            float wv = (v>=1 && v<=3)? 2.f : 1.f;
            vc = wv*cosf(ang)*0.125f; vs = -wv*sinf(ang)*0.125f;
        }
        Ci[i] = (__bf16)vc; nSi[i] = (__bf16)vs;
    }
}

// ---------------- K1: LN1 + shift + window partition + qkv GEMM (MFMA, pipelined)
__global__ __launch_bounds__(256,2) void k_qkv(const float* __restrict__ x,
        const float* __restrict__ n1g, const float* __restrict__ n1b,
        const __bf16* __restrict__ Wqt, const float* __restrict__ qkv_b,
        __bf16* __restrict__ S){
    __shared__ __align__(16) __bf16 xw[64*200];
    __shared__ __align__(16) __bf16 Wt[192*72];
    int tid = threadIdx.x;
    int win = blockIdx.x;
    int bb = win>>8, rem = win&255, wh = rem>>4, wwi = rem&15;
    {
        int tok = tid>>2, part = tid&3;
        int r = tok>>3, c = tok&7;
        int sh = (wh*8 + r + SSH)&127, sw = (wwi*8 + c + SSH)&127;
        const float* srcp = x + (((size_t)(bb*128+sh))*128 + sw)*192 + part*48;
        float v[48];
        #pragma unroll
        for (int i=0;i<12;i++){
            float4 t4 = *reinterpret_cast<const float4*>(srcp + i*4);
            v[i*4]=t4.x; v[i*4+1]=t4.y; v[i*4+2]=t4.z; v[i*4+3]=t4.w;
        }
        float s=0.f, ss=0.f;
        #pragma unroll
        for (int i=0;i<48;i++){ s+=v[i]; ss+=v[i]*v[i]; }
        s  += __shfl_xor(s,1);  s  += __shfl_xor(s,2);
        ss += __shfl_xor(ss,1); ss += __shfl_xor(ss,2);
        float mean = s*(1.f/192.f);
        float rstd = rsqrtf(ss*(1.f/192.f) - mean*mean + 1e-5f);
        #pragma unroll
        for (int i8=0;i8<6;i8++){
            bf16x8 pk;
            #pragma unroll
            for (int j=0;j<8;j++){
                int ch = part*48 + i8*8 + j;
                pk[j] = (__bf16)((v[i8*8+j]-mean)*rstd*n1g[ch] + n1b[ch]);
            }
            *reinterpret_cast<bf16x8*>(&xw[tok*200 + part*48 + i8*8]) = pk;
        }
    }
    int lane = tid&63, w = tid>>6, lr = lane&15, lg = lane>>4;
    ushort8 wreg[6];
    auto ldW = [&](int s, ushort8* wr){
        int nc = s/3, kc = s - nc*3;
        #pragma unroll
        for (int i=0;i<6;i++){
            int e = tid + i*256;
            int j = e>>3, k8 = e&7;
            wr[i] = *reinterpret_cast<const ushort8*>(
                reinterpret_cast<const unsigned short*>(Wqt) + (size_t)(nc*192+j)*192 + kc*64 + k8*8);
        }
    };
    auto stW = [&](ushort8* wr){
        #pragma unroll
        for (int i=0;i<6;i++){
            int e = tid + i*256;
            int j = e>>3, k8 = e&7;
            *reinterpret_cast<ushort8*>(reinterpret_cast<unsigned short*>(Wt) + j*72 + k8*8) = wr[i];
        }
    };
    ldW(0, wreg);
    __syncthreads();
    stW(wreg);
    __syncthreads();
    f32x4 acc[4][3];
    #pragma unroll
    for (int m=0;m<4;m++)
        #pragma unroll
        for (int n=0;n<3;n++) acc[m][n] = zero4();
    for (int s=0; s<9; s++){
        int nc = s/3, kc = s - nc*3;
        if (s<8) ldW(s+1, wreg);
        #pragma unroll
        for (int kk=0; kk<2; kk++){
            int ko = kc*64 + kk*32 + lg*8;
            bf16x8 a[4];
            #pragma unroll
            for (int m=0;m<4;m++) a[m] = ldfrag(&xw[(16*m+lr)*200 + ko]);
            int klo = kk*32 + lg*8;
            bf16x8 bfr[3];
            #pragma unroll
            for (int n=0;n<3;n++) bfr[n] = ldfrag(&Wt[(48*w+16*n+lr)*72 + klo]);
            #pragma unroll
            for (int m=0;m<4;m++)
                #pragma unroll
                for (int n=0;n<3;n++) acc[m][n] = MFMA16(a[m], bfr[n], acc[m][n]);
        }
        if (kc==2){
            #pragma unroll
            for (int n=0;n<3;n++){
                int col = nc*192 + 48*w + 16*n + lr;
                float bias = qkv_b[col];
                #pragma unroll
                for (int m=0;m<4;m++)
                    #pragma unroll
                    for (int r=0;r<4;r++){
                        int row = 16*m + 4*lg + r;
                        S[(size_t)(win*64+row)*576 + col] = (__bf16)(acc[m][n][r] + bias);
                    }
            }
            #pragma unroll
            for (int m=0;m<4;m++)
                #pragma unroll
                for (int n=0;n<3;n++) acc[m][n] = zero4();
        }
        __syncthreads();
        if (s<8) stW(wreg);
        __syncthreads();
    }
}

// ---------------- K2: spatial window attention (MFMA) from S -> Bbuf (d_out) --
__global__ __launch_bounds__(256,4) void k_spatial(const __bf16* __restrict__ S,
        const float* __restrict__ relt, const float* __restrict__ mask,
        float* __restrict__ Bbuf){
    __shared__ __align__(16) __bf16 P[64*72];    // 9216 B (wave-private row blocks)
    __shared__ __align__(16) __bf16 Vt[32*72];   // 4608 B (V transposed [d][mc])
    __shared__ float reltL[1350];                // rel-bias table [225][6]
    int tid = threadIdx.x;
    int win = blockIdx.x;
    int widx = win & 255;
    int lane = tid&63, w = tid>>6, lr = lane&15, lg = lane>>4;
    for (int e=tid; e<1350; e+=256) reltL[e] = relt[e];
    float mreg[16];
    int bidx[16];
    #pragma unroll
    for (int nt=0; nt<4; nt++)
        #pragma unroll
        for (int r=0;r<4;r++){
            int row = 16*w + 4*lg + r;
            int col = 16*nt + lr;
            mreg[nt*4+r] = mask[((widx*64 + row)<<6) + col];
            int dr = (row>>3)-(col>>3)+7, dc = (row&7)-(col&7)+7;
            bidx[nt*4+r] = (dr*15+dc)*6;
        }
    const size_t sbase = (size_t)win*64*576;
    const __bf16* Sq = S + sbase;
    const __bf16* Sk = S + sbase + 192;
    const __bf16* Sv = S + sbase + 384;
    for (int h=0; h<6; h++){
        __syncthreads();     // protect Vt against previous head's PV reads
        {   // stage Vt[d][p] (transpose of V)
            int d = tid&31, pg = tid>>5;
            const __bf16* sp = Sv + (size_t)(pg*8)*576 + h*32 + d;
            bf16x4 v0, v1;
            v0[0]=sp[0];    v0[1]=sp[576];  v0[2]=sp[1152]; v0[3]=sp[1728];
            v1[0]=sp[2304]; v1[1]=sp[2880]; v1[2]=sp[3456]; v1[3]=sp[4032];
            *reinterpret_cast<bf16x4*>(&Vt[d*72 + pg*8])   = v0;
            *reinterpret_cast<bf16x4*>(&Vt[d*72 + pg*8+4]) = v1;
        }
        __syncthreads();
        bf16x8 aq = ldfrag(Sq + (size_t)(16*w+lr)*576 + h*32 + lg*8);
        f32x4 acc[4];
        #pragma unroll
        for (int nt=0;nt<4;nt++){
            bf16x8 bk = ldfrag(Sk + (size_t)(16*nt+lr)*576 + h*32 + lg*8);
            acc[nt] = MFMA16(aq, bk, zero4());
        }
        float p[16];
        #pragma unroll
        for (int r=0;r<4;r++){
            float sc[4];
            #pragma unroll
            for (int nt=0;nt<4;nt++)
                sc[nt] = acc[nt][r]*SCALE + reltL[bidx[nt*4+r] + h] + mreg[nt*4+r];
            float mx = fmaxf(fmaxf(sc[0],sc[1]),fmaxf(sc[2],sc[3]));
            mx = fmaxf(mx, __shfl_xor(mx,1));
            mx = fmaxf(mx, __shfl_xor(mx,2));
            mx = fmaxf(mx, __shfl_xor(mx,4));
            mx = fmaxf(mx, __shfl_xor(mx,8));
            float sum = 0.f;
            #pragma unroll
            for (int nt=0;nt<4;nt++){ sc[nt] = __expf(sc[nt]-mx); sum += sc[nt]; }
            sum += __shfl_xor(sum,1);
            sum += __shfl_xor(sum,2);
            sum += __shfl_xor(sum,4);
            sum += __shfl_xor(sum,8);
            float inv = 1.f/sum;
            #pragma unroll
            for (int nt=0;nt<4;nt++) p[r*4+nt] = sc[nt]*inv;
        }
        #pragma unroll
        for (int r=0;r<4;r++)
            #pragma unroll
            for (int nt=0;nt<4;nt++)
                P[(16*w + 4*lg + r)*72 + 16*nt + lr] = (__bf16)p[r*4+nt];
        #pragma unroll
        for (int dt=0; dt<2; dt++){
            f32x4 o = zero4();
            #pragma unroll
            for (int ks=0; ks<2; ks++)
                o = MFMA16(ldfrag(&P[(16*w+lr)*72 + ks*32 + lg*8]),
                           ldfrag(&Vt[(16*dt+lr)*72 + ks*32 + lg*8]), o);
            #pragma unroll
            for (int r=0;r<4;r++){
                int row = 16*w + 4*lg + r;
                Bbuf[((size_t)win*64 + row)*192 + h*32 + 16*dt + lr] = o[r];
            }
        }
    }
}

// ------- K3: Fourier branch, fully MFMA. One block per (window, head). -------
__global__ __launch_bounds__(256,3) void k_fattn(const __bf16* __restrict__ S,
        const float* __restrict__ qkv_b,
        const __bf16* __restrict__ Fre_g, const __bf16* __restrict__ Fim_g,
        const __bf16* __restrict__ Ci_g,  const __bf16* __restrict__ nSi_g,
        float* __restrict__ Bbuf){
    __shared__ __align__(16) unsigned char arena[45056];
    __bf16* Gq_r = (__bf16*)(arena);             // [48][40]
    __bf16* Gqin = (__bf16*)(arena + 3840);      // [48][40] (negated Qi)
    __bf16* Gk_r = (__bf16*)(arena + 7680);      // [48][40]
    __bf16* Gk_i = (__bf16*)(arena + 11520);     // [48][40]
    __bf16* Rt_r = (__bf16*)(arena);             // [32][88] overlay (PV phase)
    __bf16* Rt_i = (__bf16*)(arena + 5632);      // [32][88]
    __bf16* Gv_r = (__bf16*)(arena + 15360);     // [32][88]
    __bf16* Gv_i = (__bf16*)(arena + 20992);     // [32][88]
    __bf16* St   = (__bf16*)(arena + 26624);     // [32][88] (spectra phase)
    float*  Smat = (float*) (arena + 26624);     // [48][52] overlay (QK phase)
    __bf16* P    = (__bf16*)(arena + 36608);     // [48][88]
    int tid = threadIdx.x;
    int win = blockIdx.x / 6, h = blockIdx.x - win*6;
    int lane = tid&63, w = tid>>6, lr = lane&15, lg = lane>>4;
    bf16x4 z4; z4[0]=z4[1]=z4[2]=z4[3]=(__bf16)0.f;
    {   // zero Gv^T pad cols 48..63 (K-padding for PV)
        int t2 = tid & 127;
        __bf16* A = (tid<128)? Gv_r : Gv_i;
        int row = t2>>2, c4 = (t2&3)*4;
        *reinterpret_cast<bf16x4*>(A + row*88 + 48 + c4) = z4;
    }
    const size_t sbase = (size_t)win*64*576 + h*32;
    for (int m=0;m<3;m++){
        __syncthreads();
        {   // transpose-stage: St[d][p]
            int d = tid&31, pg = tid>>5;
            const __bf16* sp = S + sbase + (size_t)m*192 + (size_t)pg*8*576 + d;
            bf16x4 v0, v1;
            v0[0]=sp[0];      v0[1]=sp[576];    v0[2]=sp[1152];   v0[3]=sp[1728];
            v1[0]=sp[2304];   v1[1]=sp[2880];   v1[2]=sp[3456];   v1[3]=sp[4032];
            *reinterpret_cast<bf16x4*>(&St[d*88 + pg*8])     = v0;
            *reinterpret_cast<bf16x4*>(&St[d*88 + pg*8 + 4]) = v1;
        }
        __syncthreads();
        for (int j=w; j<12; j+=4){
            int term = j/6, r2 = j - term*6;
            if (m<2){
                int mt = r2>>1, nt = r2&1;
                const __bf16* Ag = (term? Fim_g : Fre_g) + (16*mt+lr)*64 + lg*8;
                f32x4 acc = zero4();
                acc = MFMA16(*reinterpret_cast<const bf16x8*>(Ag),
                             ldfrag(&St[(16*nt+lr)*88 + lg*8]), acc);
                acc = MFMA16(*reinterpret_cast<const bf16x8*>(Ag+32),
                             ldfrag(&St[(16*nt+lr)*88 + 32 + lg*8]), acc);
                int d = 16*nt + lr;
                float b = qkv_b[m*192 + h*32 + d];
                __bf16* dst = (m==0)? (term? Gqin : Gq_r) : (term? Gk_i : Gk_r);
                #pragma unroll
                for (int r=0;r<4;r++){
                    int n = 16*mt + 4*lg + r;
                    float val = acc[r] + ((term==0) ? ((n==0)? -7.f*b : b) : b);
                    if (m==0 && term==1) val = -val;     // store -Qi
                    dst[n*40 + d] = (__bf16)val;
                }
            } else {
                int mt = r2/3, nt = r2 - mt*3;
                const __bf16* Bg = (term? Fim_g : Fre_g) + (16*nt+lr)*64 + lg*8;
                f32x4 acc = zero4();
                acc = MFMA16(ldfrag(&St[(16*mt+lr)*88 + lg*8]),
                             *reinterpret_cast<const bf16x8*>(Bg), acc);
                acc = MFMA16(ldfrag(&St[(16*mt+lr)*88 + 32 + lg*8]),
                             *reinterpret_cast<const bf16x8*>(Bg+32), acc);
                int n = 16*nt + lr;
                __bf16* dst = term? Gv_i : Gv_r;
                #pragma unroll
                for (int r=0;r<4;r++){
                    int d = 16*mt + 4*lg + r;
                    float b = qkv_b[2*192 + h*32 + d];
                    float val = acc[r] + ((term==0) ? ((n==0)? -7.f*b : b) : b);
                    dst[d*88 + n] = (__bf16)val;
                }
            }
        }
    }
    __syncthreads();
    for (int j=w; j<9; j+=4){
        int mt = j/3, nt = j - mt*3;
        bf16x8 qr = ldfrag(&Gq_r[(16*mt+lr)*40 + lg*8]);
        bf16x8 qi = ldfrag(&Gqin[(16*mt+lr)*40 + lg*8]);
        bf16x8 kr = ldfrag(&Gk_r[(16*nt+lr)*40 + lg*8]);
        bf16x8 ki = ldfrag(&Gk_i[(16*nt+lr)*40 + lg*8]);
        f32x4 sre = MFMA16(qi, ki, zero4());   // (-Qi).Ki
        sre = MFMA16(qr, kr, sre);             // + Qr.Kr
        f32x4 t1 = MFMA16(qr, ki, zero4());    // Qr.Ki
        f32x4 t2 = MFMA16(qi, kr, zero4());    // (-Qi).Kr
        #pragma unroll
        for (int r=0;r<4;r++){
            float sim = t1[r] - t2[r];
            Smat[(16*mt + 4*lg + r)*52 + 16*nt + lr] =
                SCALE * sqrtf(sre[r]*sre[r] + sim*sim);
        }
    }
    __syncthreads();
    if (tid < 160){
        int row = tid>>2, part = tid&3, e0 = part*10;
        float mx = -1e30f;
        #pragma unroll
        for (int j=0;j<10;j++) mx = fmaxf(mx, Smat[row*52 + e0 + j]);
        mx = fmaxf(mx, __shfl_xor(mx,1));
        mx = fmaxf(mx, __shfl_xor(mx,2));
        float ex[10]; float sum=0.f;
        #pragma unroll
        for (int j=0;j<10;j++){ ex[j] = __expf(Smat[row*52+e0+j]-mx); sum += ex[j]; }
        sum += __shfl_xor(sum,1);
        sum += __shfl_xor(sum,2);
        float inv = 1.f/sum;
        #pragma unroll
        for (int j=0;j<10;j++) Smat[row*52+e0+j] = ex[j]*inv;
    }
    __syncthreads();
    for (int e=tid; e<3072; e+=256){
        int row = e>>6, col = e&63;
        float v = (row<40 && col<40)? Smat[row*52+col] : 0.f;
        P[row*88+col] = (__bf16)v;
    }
    {
        int t2 = tid & 127;
        __bf16* A = (tid<128)? Rt_r : Rt_i;
        int row = t2>>2, c4 = (t2&3)*4;
        *reinterpret_cast<bf16x4*>(A + row*88 + 48 + c4) = z4;
    }
    __syncthreads();
    for (int j=w; j<12; j+=4){
        int term = j/6, r2 = j - term*6;
        int dt = r2/3, nt = r2 - dt*3;
        const __bf16* Gv = term? Gv_i : Gv_r;
        f32x4 acc = zero4();
        #pragma unroll
        for (int ks=0; ks<2; ks++)
            acc = MFMA16(ldfrag(&Gv[(16*dt+lr)*88 + ks*32 + lg*8]),
                         ldfrag(&P [(16*nt+lr)*88 + ks*32 + lg*8]), acc);
        __bf16* dst = term? Rt_i : Rt_r;
        #pragma unroll
        for (int r=0;r<4;r++)
            dst[(16*dt + 4*lg + r)*88 + 16*nt + lr] = (__bf16)acc[r];
    }
    __syncthreads();
    for (int j=w; j<8; j+=4){
        int dt = j>>2, pt = j&3;
        f32x4 acc = zero4();
        #pragma unroll
        for (int ks=0; ks<2; ks++)
            acc = MFMA16(*reinterpret_cast<const bf16x8*>(nSi_g + (16*pt+lr)*64 + ks*32 + lg*8),
                         ldfrag(&Rt_i[(16*dt+lr)*88 + ks*32 + lg*8]), acc);
        #pragma unroll
        for (int ks=0; ks<2; ks++)
            acc = MFMA16(*reinterpret_cast<const bf16x8*>(Ci_g + (16*pt+lr)*64 + ks*32 + lg*8),
                         ldfrag(&Rt_r[(16*dt+lr)*88 + ks*32 + lg*8]), acc);
        #pragma unroll
        for (int r=0;r<4;r++){
            int p = 16*pt + 4*lg + r, d = 16*dt + lr;
            size_t idx = ((size_t)win*64 + p)*192 + h*32 + d;
            Bbuf[idx] += acc[r];
        }
    }
}

// ---------------- K4: proj (MFMA, pipelined) + window reverse + unshift + residual -> X1
__global__ __launch_bounds__(256,2) void k_proj(const float* __restrict__ Bbuf,
        const float* __restrict__ x, const __bf16* __restrict__ Wpt,
        const float* __restrict__ proj_b, float* __restrict__ X1){
    __shared__ __align__(16) __bf16 xt[64*200];
    __shared__ __align__(16) __bf16 Wt[192*72];
    int tid = threadIdx.x;
    int win = blockIdx.x;
    {
        int tok = tid>>2, part = tid&3;
        const float* srcp = Bbuf + ((size_t)win*64 + tok)*192 + part*48;
        #pragma unroll
        for (int i8=0;i8<6;i8++){
            float4 a4 = *reinterpret_cast<const float4*>(srcp + i8*8);
            float4 b4 = *reinterpret_cast<const float4*>(srcp + i8*8 + 4);
            bf16x8 pk;
            pk[0]=(__bf16)a4.x; pk[1]=(__bf16)a4.y; pk[2]=(__bf16)a4.z; pk[3]=(__bf16)a4.w;
            pk[4]=(__bf16)b4.x; pk[5]=(__bf16)b4.y; pk[6]=(__bf16)b4.z; pk[7]=(__bf16)b4.w;
            *reinterpret_cast<bf16x8*>(&xt[tok*200 + part*48 + i8*8]) = pk;
        }
    }
    int lane = tid&63, w = tid>>6, lr = lane&15, lg = lane>>4;
    ushort8 wreg[6];
    auto ldW = [&](int kc, ushort8* wr){
        #pragma unroll
        for (int i=0;i<6;i++){
            int e = tid + i*256;
            int j = e>>3, k8 = e&7;
            wr[i] = *reinterpret_cast<const ushort8*>(
                reinterpret_cast<const unsigned short*>(Wpt) + (size_t)j*192 + kc*64 + k8*8);
        }
    };
    auto stW = [&](ushort8* wr){
        #pragma unroll
        for (int i=0;i<6;i++){
            int e = tid + i*256;
            int j = e>>3, k8 = e&7;
            *reinterpret_cast<ushort8*>(reinterpret_cast<unsigned short*>(Wt) + j*72 + k8*8) = wr[i];
        }
    };
    ldW(0, wreg);
    __syncthreads();
    stW(wreg);
    __syncthreads();
    f32x4 acc[4][3];
    #pragma unroll
    for (int m=0;m<4;m++)
        #pragma unroll
        for (int n=0;n<3;n++) acc[m][n] = zero4();
    for (int kc=0; kc<3; kc++){
        if (kc<2) ldW(kc+1, wreg);
        #pragma unroll
        for (int kk=0; kk<2; kk++){
            int ko = kc*64 + kk*32 + lg*8;
            bf16x8 a[4];
            #pragma unroll
            for (int m=0;m<4;m++) a[m] = ldfrag(&xt[(16*m+lr)*200 + ko]);
            int klo = kk*32 + lg*8;
            bf16x8 bfr[3];
            #pragma unroll
            for (int n=0;n<3;n++) bfr[n] = ldfrag(&Wt[(48*w+16*n+lr)*72 + klo]);
            #pragma unroll
            for (int m=0;m<4;m++)
                #pragma unroll
                for (int n=0;n<3;n++) acc[m][n] = MFMA16(a[m], bfr[n], acc[m][n]);
        }
        __syncthreads();
        if (kc<2) stW(wreg);
        __syncthreads();
    }
    int bb = win>>8, rem = win&255, wh = rem>>4, wwi = rem&15;
    #pragma unroll
    for (int m=0;m<4;m++)
        #pragma unroll
        for (int r=0;r<4;r++){
            int t = 16*m + 4*lg + r;
            int p = wh*8 + (t>>3), q = wwi*8 + (t&7);
            int hh = (p+SSH)&127, w2 = (q+SSH)&127;
            size_t pixb = (((size_t)bb*128 + hh)*128 + w2)*192;
            #pragma unroll
            for (int n=0;n<3;n++){
                int col = 48*w + 16*n + lr;
                X1[pixb + col] = acc[m][n][r] + proj_b[col] + x[pixb + col];
            }
        }
}

// ---------------- K5: LN2 + fc1(MFMA) + fast GELU + fc2(MFMA) + residual -----
__global__ __launch_bounds__(256,2) void k_mlp(const float* __restrict__ X1,
        const float* __restrict__ g2, const float* __restrict__ b2v,
        const __bf16* __restrict__ W1t, const float* __restrict__ fc1b,
        const __bf16* __restrict__ W2t, const float* __restrict__ fc2b,
        float* __restrict__ out){
    __shared__ __align__(16) __bf16 xln[64*200];
    __shared__ __align__(16) __bf16 hbuf[64*200];
    __shared__ __align__(16) __bf16 Wt[192*72];
    int tid = threadIdx.x;
    size_t base = (size_t)blockIdx.x*64;
    {
        int tok = tid>>2, part = tid&3;
        const float* srcp = X1 + (base + tok)*192 + part*48;
        float v[48];
        #pragma unroll
        for (int i=0;i<12;i++){
            float4 t4 = *reinterpret_cast<const float4*>(srcp + i*4);
            v[i*4]=t4.x; v[i*4+1]=t4.y; v[i*4+2]=t4.z; v[i*4+3]=t4.w;
        }
        float s=0.f, ss=0.f;
        #pragma unroll
        for (int i=0;i<48;i++){ s+=v[i]; ss+=v[i]*v[i]; }
        s  += __shfl_xor(s,1);  s  += __shfl_xor(s,2);
        ss += __shfl_xor(ss,1); ss += __shfl_xor(ss,2);
        float mean = s*(1.f/192.f);
        float rstd = rsqrtf(ss*(1.f/192.f) - mean*mean + 1e-5f);
        #pragma unroll
        for (int i8=0;i8<6;i8++){
            bf16x8 pk;
            #pragma unroll
            for (int j=0;j<8;j++){
                int ch = part*48 + i8*8 + j;
                pk[j] = (__bf16)((v[i8*8+j]-mean)*rstd*g2[ch] + b2v[ch]);
            }
            *reinterpret_cast<bf16x8*>(&xln[tok*200 + part*48 + i8*8]) = pk;
        }
    }
    int lane = tid&63, w = tid>>6, lr = lane&15, lg = lane>>4;
    ushort8 wreg[6];
    auto ldW = [&](int s, ushort8* wr){
        int hc = s/6, inner = s - hc*6;
        int kc = (inner<3)? inner : inner-3;
        const unsigned short* src;
        size_t rowstride;
        size_t off;
        if (inner<3){ src = reinterpret_cast<const unsigned short*>(W1t);
                      rowstride = 192; off = (size_t)(hc*192)*192 + kc*64; }
        else        { src = reinterpret_cast<const unsigned short*>(W2t);
                      rowstride = 768; off = (size_t)hc*192 + kc*64; }
        #pragma unroll
        for (int i=0;i<6;i++){
            int e = tid + i*256;
            int j = e>>3, k8 = e&7;
            wr[i] = *reinterpret_cast<const ushort8*>(src + (size_t)j*rowstride + off + k8*8);
        }
    };
    auto stW = [&](ushort8* wr){
        #pragma unroll
        for (int i=0;i<6;i++){
            int e = tid + i*256;
            int j = e>>3, k8 = e&7;
            *reinterpret_cast<ushort8*>(reinterpret_cast<unsigned short*>(Wt) + j*72 + k8*8) = wr[i];
        }
    };
    ldW(0, wreg);
    __syncthreads();
    stW(wreg);
    __syncthreads();
    f32x4 acc1[4][3], acc2[4][3];
    #pragma unroll
    for (int m=0;m<4;m++)
        #pragma unroll
        for (int n=0;n<3;n++){ acc1[m][n] = zero4(); acc2[m][n] = zero4(); }
    for (int s=0; s<24; s++){
        int hc = s/6, inner = s - hc*6;
        bool fc1 = inner<3;
        int kc = fc1 ? inner : inner-3;
        if (s<23) ldW(s+1, wreg);
        const __bf16* A = fc1 ? xln : hbuf;
        #pragma unroll
        for (int kk=0; kk<2; kk++){
            int ko = kc*64 + kk*32 + lg*8;
            bf16x8 a[4];
            #pragma unroll
            for (int m=0;m<4;m++) a[m] = ldfrag(&A[(16*m+lr)*200 + ko]);
            int klo = kk*32 + lg*8;
            bf16x8 bfr[3];
            #pragma unroll
            for (int n=0;n<3;n++) bfr[n] = ldfrag(&Wt[(48*w+16*n+lr)*72 + klo]);
            if (fc1){
                #pragma unroll
                for (int m=0;m<4;m++)
                    #pragma unroll
                    for (int n=0;n<3;n++) acc1[m][n] = MFMA16(a[m], bfr[n], acc1[m][n]);
            } else {
                #pragma unroll
                for (int m=0;m<4;m++)
                    #pragma unroll
                    for (int n=0;n<3;n++) acc2[m][n] = MFMA16(a[m], bfr[n], acc2[m][n]);
            }
        }
        if (inner==2){
            #pragma unroll
            for (int n=0;n<3;n++){
                int jcol = 48*w + 16*n + lr;
                float b1 = fc1b[hc*192 + jcol];
                #pragma unroll
                for (int m=0;m<4;m++)
                    #pragma unroll
                    for (int r=0;r<4;r++){
                        float xv = acc1[m][n][r] + b1;
                        hbuf[(16*m + 4*lg + r)*200 + jcol] = (__bf16)gelu_fast(xv);
                        acc1[m][n][r] = 0.f;
                    }
            }
        }
        __syncthreads();
        if (s<23) stW(wreg);
        __syncthreads();
    }
    #pragma unroll
    for (int n=0;n<3;n++){
        int col = 48*w + 16*n + lr;
        float b2 = fc2b[col];
        #pragma unroll
        for (int m=0;m<4;m++)
            #pragma unroll
            for (int r=0;r<4;r++){
                size_t t = base + 16*m + 4*lg + r;
                out[t*192 + col] = acc2[m][n][r] + b2 + X1[t*192 + col];
            }
    }
}

extern "C" void kernel_launch(void* const* d_in, const int* in_sizes, int n_in,
                              void* d_out, int out_size, void* d_ws, size_t ws_size,
                              hipStream_t stream) {
    const float* x     = (const float*)d_in[0];
    const float* mask  = (const float*)d_in[1];
    const float* n1g   = (const float*)d_in[2];
    const float* n1b   = (const float*)d_in[3];
    const float* qkvw  = (const float*)d_in[4];
    const float* qkvb  = (const float*)d_in[5];
    const float* relt  = (const float*)d_in[6];
    const float* projw = (const float*)d_in[7];
    const float* projb = (const float*)d_in[8];
    const float* n2g   = (const float*)d_in[9];
    const float* n2b   = (const float*)d_in[10];
    const float* fc1w  = (const float*)d_in[11];
    const float* fc1b  = (const float*)d_in[12];
    const float* fc2w  = (const float*)d_in[13];
    const float* fc2b  = (const float*)d_in[14];
    float* out = (float*)d_out;

    char* wsb = (char*)d_ws;
    __bf16* Sb  = (__bf16*)wsb;                        // 150,994,944 B
    float*  X1  = (float*)(wsb + 150994944);           // 100,663,296 B
    __bf16* Wqt = (__bf16*)(wsb + 251658240);          //    221,184 B
    __bf16* Wpt = (__bf16*)(wsb + 251879424);          //     73,728 B
    __bf16* W1t = (__bf16*)(wsb + 251953152);          //    294,912 B
    __bf16* W2t = (__bf16*)(wsb + 252248064);          //    294,912 B
    __bf16* Fre = (__bf16*)(wsb + 252542976);          //      6,144 B
    __bf16* Fim = (__bf16*)(wsb + 252549120);          //      6,144 B
    __bf16* Ci  = (__bf16*)(wsb + 252555264);          //      8,192 B
    __bf16* nSi = (__bf16*)(wsb + 252563456);          //      8,192 B

    k_prep   <<<576,   256, 0, stream>>>(qkvw, projw, fc1w, fc2w, Wqt, Wpt, W1t, W2t,
                                         Fre, Fim, Ci, nSi);
    k_qkv    <<<2048,  256, 0, stream>>>(x, n1g, n1b, Wqt, qkvb, Sb);
    k_spatial<<<2048,  256, 0, stream>>>(Sb, relt, mask, out);
    k_fattn  <<<12288, 256, 0, stream>>>(Sb, qkvb, Fre, Fim, Ci, nSi, out);
    k_proj   <<<2048,  256, 0, stream>>>(out, x, Wpt, projb, X1);
    k_mlp    <<<2048,  256, 0, stream>>>(X1, n2g, n2b, W1t, fc1b, W2t, fc2b, out);
}

// Round 10
// 607.300 us; speedup vs baseline: 6.1016x; 1.0157x over previous
//
#include <hip/hip_runtime.h>
#include <hip/hip_bf16.h>
#include <math.h>

#define SSH 4
#define SCALE 0.17677669529663687f  // 1/sqrt(32)

typedef __bf16 bf16x8 __attribute__((ext_vector_type(8)));
typedef __bf16 bf16x4 __attribute__((ext_vector_type(4)));
typedef unsigned short ushort8 __attribute__((ext_vector_type(8)));
typedef float  f32x4  __attribute__((ext_vector_type(4)));

static __device__ __forceinline__ f32x4 mfma16(bf16x8 a, bf16x8 b, f32x4 c){
    return __builtin_amdgcn_mfma_f32_16x16x32_bf16(a, b, c, 0, 0, 0);
}
#define MFMA16(a,b,c) mfma16((a),(b),(c))

static __device__ __forceinline__ bf16x8 ldfrag(const __bf16* p){
    return *reinterpret_cast<const bf16x8*>(p);
}
static __device__ __forceinline__ f32x4 zero4(){
    f32x4 z; z[0]=0.f; z[1]=0.f; z[2]=0.f; z[3]=0.f; return z;
}
// tanh-form GELU via sigmoid identity: 0.5x(1+tanh(u)) == x * sigma(2u)
static __device__ __forceinline__ float gelu_fast(float x){
    float u = x*(0.7978845608f + 0.0356774081f*x*x);
    return __fdividef(x, 1.f + __expf(-2.f*u));
}

// ---------------- K0: weight prep (bf16 [N][K]) + Fourier constant tables ----
__global__ __launch_bounds__(256) void k_prep(const float* __restrict__ qkvw,
        const float* __restrict__ projw, const float* __restrict__ fc1w,
        const float* __restrict__ fc2w, __bf16* __restrict__ Wq,
        __bf16* __restrict__ Wp, __bf16* __restrict__ W1, __bf16* __restrict__ W2,
        __bf16* __restrict__ Fre, __bf16* __restrict__ Fim,
        __bf16* __restrict__ Ci,  __bf16* __restrict__ nSi){
    int i = blockIdx.x*256 + threadIdx.x;
    if (i < 110592){ int n = i/192, k = i - n*192; Wq[i] = (__bf16)qkvw[k*576 + n]; }
    if (i < 36864) { int n = i/192, k = i - n*192; Wp[i] = (__bf16)projw[k*192 + n]; }
    if (i < 147456){ int n = i/192, k = i - n*192; W1[i] = (__bf16)fc1w[k*768 + n]; }
    if (i < 147456){ int n = i/768, k = i - n*768; W2[i] = (__bf16)fc2w[k*192 + n]; }
    if (i < 3072){
        int n = i>>6, p = i&63;
        float vr = 0.f, vi = 0.f;
        if (n < 40){
            int u = n/5, v = n - u*5, r = p>>3, c = p&7;
            int k = (u*r + v*c)&7;
            float ang = (float)k * 0.78539816339744831f;
            vr = cosf(ang)*0.125f; vi = -sinf(ang)*0.125f;
        }
        Fre[i] = (__bf16)vr; Fim[i] = (__bf16)vi;
    }
    if (i < 4096){
        int p = i>>6, n = i&63;
        float vc = 0.f, vs = 0.f;
        if (n < 40){
            int u = n/5, v = n - u*5, r = p>>3, c = p&7;
            int k = (u*r + v*c)&7;
            float ang = (float)k * 0.78539816339744831f;
            float wv = (v>=1 && v<=3)? 2.f : 1.f;
            vc = wv*cosf(ang)*0.125f; vs = -wv*sinf(ang)*0.125f;
        }
        Ci[i] = (__bf16)vc; nSi[i] = (__bf16)vs;
    }
}

// ---------------- K1: LN1 + shift + qkv GEMM (MFMA), 128 tokens/block --------
__global__ __launch_bounds__(512,4) void k_qkv(const float* __restrict__ x,
        const float* __restrict__ n1g, const float* __restrict__ n1b,
        const __bf16* __restrict__ Wqt, const float* __restrict__ qkv_b,
        __bf16* __restrict__ S){
    __shared__ __align__(16) __bf16 xw[128*200];
    __shared__ __align__(16) __bf16 Wt[192*72];
    int tid = threadIdx.x;
    int blk = blockIdx.x;
    {   // LN1 on 128 shifted window tokens (4 threads per token)
        int tok = tid>>2, part = tid&3;
        int win = blk*2 + (tok>>6), ti = tok&63;
        int bb = win>>8, rem = win&255, wh = rem>>4, wwi = rem&15;
        int r = ti>>3, c = ti&7;
        int sh = (wh*8 + r + SSH)&127, sw = (wwi*8 + c + SSH)&127;
        const float* srcp = x + (((size_t)(bb*128+sh))*128 + sw)*192 + part*48;
        float v[48];
        #pragma unroll
        for (int i=0;i<12;i++){
            float4 t4 = *reinterpret_cast<const float4*>(srcp + i*4);
            v[i*4]=t4.x; v[i*4+1]=t4.y; v[i*4+2]=t4.z; v[i*4+3]=t4.w;
        }
        float s=0.f, ss=0.f;
        #pragma unroll
        for (int i=0;i<48;i++){ s+=v[i]; ss+=v[i]*v[i]; }
        s  += __shfl_xor(s,1);  s  += __shfl_xor(s,2);
        ss += __shfl_xor(ss,1); ss += __shfl_xor(ss,2);
        float mean = s*(1.f/192.f);
        float rstd = rsqrtf(ss*(1.f/192.f) - mean*mean + 1e-5f);
        #pragma unroll
        for (int i8=0;i8<6;i8++){
            bf16x8 pk;
            #pragma unroll
            for (int j=0;j<8;j++){
                int ch = part*48 + i8*8 + j;
                pk[j] = (__bf16)((v[i8*8+j]-mean)*rstd*n1g[ch] + n1b[ch]);
            }
            *reinterpret_cast<bf16x8*>(&xw[tok*200 + part*48 + i8*8]) = pk;
        }
    }
    int lane = tid&63, w = tid>>6, lr = lane&15, lg = lane>>4;
    int rowb = (w>>2)*64, wq = w&3;
    ushort8 wreg[3];
    auto ldW = [&](int s, ushort8* wr){
        int nc = s/3, kc = s - nc*3;
        #pragma unroll
        for (int i=0;i<3;i++){
            int e = tid + i*512;            // 1536 vec8 units
            int j = e>>3, k8 = e&7;
            wr[i] = *reinterpret_cast<const ushort8*>(
                reinterpret_cast<const unsigned short*>(Wqt) + (size_t)(nc*192+j)*192 + kc*64 + k8*8);
        }
    };
    auto stW = [&](ushort8* wr){
        #pragma unroll
        for (int i=0;i<3;i++){
            int e = tid + i*512;
            int j = e>>3, k8 = e&7;
            *reinterpret_cast<ushort8*>(reinterpret_cast<unsigned short*>(Wt) + j*72 + k8*8) = wr[i];
        }
    };
    ldW(0, wreg);
    __syncthreads();
    stW(wreg);
    __syncthreads();
    f32x4 acc[4][3];
    #pragma unroll
    for (int m=0;m<4;m++)
        #pragma unroll
        for (int n=0;n<3;n++) acc[m][n] = zero4();
    for (int s=0; s<9; s++){
        int nc = s/3, kc = s - nc*3;
        if (s<8) ldW(s+1, wreg);
        #pragma unroll
        for (int kk=0; kk<2; kk++){
            int ko = kc*64 + kk*32 + lg*8;
            bf16x8 a[4];
            #pragma unroll
            for (int m=0;m<4;m++) a[m] = ldfrag(&xw[(rowb+16*m+lr)*200 + ko]);
            int klo = kk*32 + lg*8;
            bf16x8 bfr[3];
            #pragma unroll
            for (int n=0;n<3;n++) bfr[n] = ldfrag(&Wt[(48*wq+16*n+lr)*72 + klo]);
            #pragma unroll
            for (int m=0;m<4;m++)
                #pragma unroll
                for (int n=0;n<3;n++) acc[m][n] = MFMA16(a[m], bfr[n], acc[m][n]);
        }
        if (kc==2){
            #pragma unroll
            for (int n=0;n<3;n++){
                int col = nc*192 + 48*wq + 16*n + lr;
                float bias = qkv_b[col];
                #pragma unroll
                for (int m=0;m<4;m++)
                    #pragma unroll
                    for (int r=0;r<4;r++){
                        size_t row = (size_t)blk*128 + rowb + 16*m + 4*lg + r;
                        S[row*576 + col] = (__bf16)(acc[m][n][r] + bias);
                    }
            }
            #pragma unroll
            for (int m=0;m<4;m++)
                #pragma unroll
                for (int n=0;n<3;n++) acc[m][n] = zero4();
        }
        __syncthreads();
        if (s<8) stW(wreg);
        __syncthreads();
    }
}

// ---------------- K2: spatial window attention (MFMA) from S -> Bbuf (d_out) --
__global__ __launch_bounds__(256,4) void k_spatial(const __bf16* __restrict__ S,
        const float* __restrict__ relt, const float* __restrict__ mask,
        float* __restrict__ Bbuf){
    __shared__ __align__(16) __bf16 P[64*72];
    __shared__ __align__(16) __bf16 Vt[32*72];
    __shared__ float reltL[1350];
    int tid = threadIdx.x;
    int win = blockIdx.x;
    int widx = win & 255;
    int lane = tid&63, w = tid>>6, lr = lane&15, lg = lane>>4;
    for (int e=tid; e<1350; e+=256) reltL[e] = relt[e];
    float mreg[16];
    int bidx[16];
    #pragma unroll
    for (int nt=0; nt<4; nt++)
        #pragma unroll
        for (int r=0;r<4;r++){
            int row = 16*w + 4*lg + r;
            int col = 16*nt + lr;
            mreg[nt*4+r] = mask[((widx*64 + row)<<6) + col];
            int dr = (row>>3)-(col>>3)+7, dc = (row&7)-(col&7)+7;
            bidx[nt*4+r] = (dr*15+dc)*6;
        }
    const size_t sbase = (size_t)win*64*576;
    const __bf16* Sq = S + sbase;
    const __bf16* Sk = S + sbase + 192;
    const __bf16* Sv = S + sbase + 384;
    for (int h=0; h<6; h++){
        __syncthreads();
        {   // stage Vt[d][p] (transpose of V)
            int d = tid&31, pg = tid>>5;
            const __bf16* sp = Sv + (size_t)(pg*8)*576 + h*32 + d;
            bf16x4 v0, v1;
            v0[0]=sp[0];    v0[1]=sp[576];  v0[2]=sp[1152]; v0[3]=sp[1728];
            v1[0]=sp[2304]; v1[1]=sp[2880]; v1[2]=sp[3456]; v1[3]=sp[4032];
            *reinterpret_cast<bf16x4*>(&Vt[d*72 + pg*8])   = v0;
            *reinterpret_cast<bf16x4*>(&Vt[d*72 + pg*8+4]) = v1;
        }
        __syncthreads();
        bf16x8 aq = ldfrag(Sq + (size_t)(16*w+lr)*576 + h*32 + lg*8);
        f32x4 acc[4];
        #pragma unroll
        for (int nt=0;nt<4;nt++){
            bf16x8 bk = ldfrag(Sk + (size_t)(16*nt+lr)*576 + h*32 + lg*8);
            acc[nt] = MFMA16(aq, bk, zero4());
        }
        float p[16];
        #pragma unroll
        for (int r=0;r<4;r++){
            float sc[4];
            #pragma unroll
            for (int nt=0;nt<4;nt++)
                sc[nt] = acc[nt][r]*SCALE + reltL[bidx[nt*4+r] + h] + mreg[nt*4+r];
            float mx = fmaxf(fmaxf(sc[0],sc[1]),fmaxf(sc[2],sc[3]));
            mx = fmaxf(mx, __shfl_xor(mx,1));
            mx = fmaxf(mx, __shfl_xor(mx,2));
            mx = fmaxf(mx, __shfl_xor(mx,4));
            mx = fmaxf(mx, __shfl_xor(mx,8));
            float sum = 0.f;
            #pragma unroll
            for (int nt=0;nt<4;nt++){ sc[nt] = __expf(sc[nt]-mx); sum += sc[nt]; }
            sum += __shfl_xor(sum,1);
            sum += __shfl_xor(sum,2);
            sum += __shfl_xor(sum,4);
            sum += __shfl_xor(sum,8);
            float inv = 1.f/sum;
            #pragma unroll
            for (int nt=0;nt<4;nt++) p[r*4+nt] = sc[nt]*inv;
        }
        #pragma unroll
        for (int r=0;r<4;r++)
            #pragma unroll
            for (int nt=0;nt<4;nt++)
                P[(16*w + 4*lg + r)*72 + 16*nt + lr] = (__bf16)p[r*4+nt];
        #pragma unroll
        for (int dt=0; dt<2; dt++){
            f32x4 o = zero4();
            #pragma unroll
            for (int ks=0; ks<2; ks++)
                o = MFMA16(ldfrag(&P[(16*w+lr)*72 + ks*32 + lg*8]),
                           ldfrag(&Vt[(16*dt+lr)*72 + ks*32 + lg*8]), o);
            #pragma unroll
            for (int r=0;r<4;r++){
                int row = 16*w + 4*lg + r;
                Bbuf[((size_t)win*64 + row)*192 + h*32 + 16*dt + lr] = o[r];
            }
        }
    }
}

// ------- K3: Fourier branch, fully MFMA. One block per (window, head). -------
__global__ __launch_bounds__(256,3) void k_fattn(const __bf16* __restrict__ S,
        const float* __restrict__ qkv_b,
        const __bf16* __restrict__ Fre_g, const __bf16* __restrict__ Fim_g,
        const __bf16* __restrict__ Ci_g,  const __bf16* __restrict__ nSi_g,
        float* __restrict__ Bbuf){
    __shared__ __align__(16) unsigned char arena[45056];
    __bf16* Gq_r = (__bf16*)(arena);             // [48][40]
    __bf16* Gqin = (__bf16*)(arena + 3840);      // [48][40] (negated Qi)
    __bf16* Gk_r = (__bf16*)(arena + 7680);      // [48][40]
    __bf16* Gk_i = (__bf16*)(arena + 11520);     // [48][40]
    __bf16* Rt_r = (__bf16*)(arena);             // [32][88] overlay (PV phase)
    __bf16* Rt_i = (__bf16*)(arena + 5632);      // [32][88]
    __bf16* Gv_r = (__bf16*)(arena + 15360);     // [32][88]
    __bf16* Gv_i = (__bf16*)(arena + 20992);     // [32][88]
    __bf16* St   = (__bf16*)(arena + 26624);     // [32][88] (spectra phase)
    float*  Smat = (float*) (arena + 26624);     // [48][52] overlay (QK phase)
    __bf16* P    = (__bf16*)(arena + 36608);     // [48][88]
    int tid = threadIdx.x;
    int win = blockIdx.x / 6, h = blockIdx.x - win*6;
    int lane = tid&63, w = tid>>6, lr = lane&15, lg = lane>>4;
    bf16x4 z4; z4[0]=z4[1]=z4[2]=z4[3]=(__bf16)0.f;
    {
        int t2 = tid & 127;
        __bf16* A = (tid<128)? Gv_r : Gv_i;
        int row = t2>>2, c4 = (t2&3)*4;
        *reinterpret_cast<bf16x4*>(A + row*88 + 48 + c4) = z4;
    }
    const size_t sbase = (size_t)win*64*576 + h*32;
    for (int m=0;m<3;m++){
        __syncthreads();
        {
            int d = tid&31, pg = tid>>5;
            const __bf16* sp = S + sbase + (size_t)m*192 + (size_t)pg*8*576 + d;
            bf16x4 v0, v1;
            v0[0]=sp[0];      v0[1]=sp[576];    v0[2]=sp[1152];   v0[3]=sp[1728];
            v1[0]=sp[2304];   v1[1]=sp[2880];   v1[2]=sp[3456];   v1[3]=sp[4032];
            *reinterpret_cast<bf16x4*>(&St[d*88 + pg*8])     = v0;
            *reinterpret_cast<bf16x4*>(&St[d*88 + pg*8 + 4]) = v1;
        }
        __syncthreads();
        for (int j=w; j<12; j+=4){
            int term = j/6, r2 = j - term*6;
            if (m<2){
                int mt = r2>>1, nt = r2&1;
                const __bf16* Ag = (term? Fim_g : Fre_g) + (16*mt+lr)*64 + lg*8;
                f32x4 acc = zero4();
                acc = MFMA16(*reinterpret_cast<const bf16x8*>(Ag),
                             ldfrag(&St[(16*nt+lr)*88 + lg*8]), acc);
                acc = MFMA16(*reinterpret_cast<const bf16x8*>(Ag+32),
                             ldfrag(&St[(16*nt+lr)*88 + 32 + lg*8]), acc);
                int d = 16*nt + lr;
                float b = qkv_b[m*192 + h*32 + d];
                __bf16* dst = (m==0)? (term? Gqin : Gq_r) : (term? Gk_i : Gk_r);
                #pragma unroll
                for (int r=0;r<4;r++){
                    int n = 16*mt + 4*lg + r;
                    float val = acc[r] + ((term==0) ? ((n==0)? -7.f*b : b) : b);
                    if (m==0 && term==1) val = -val;     // store -Qi
                    dst[n*40 + d] = (__bf16)val;
                }
            } else {
                int mt = r2/3, nt = r2 - mt*3;
                const __bf16* Bg = (term? Fim_g : Fre_g) + (16*nt+lr)*64 + lg*8;
                f32x4 acc = zero4();
                acc = MFMA16(ldfrag(&St[(16*mt+lr)*88 + lg*8]),
                             *reinterpret_cast<const bf16x8*>(Bg), acc);
                acc = MFMA16(ldfrag(&St[(16*mt+lr)*88 + 32 + lg*8]),
                             *reinterpret_cast<const bf16x8*>(Bg+32), acc);
                int n = 16*nt + lr;
                __bf16* dst = term? Gv_i : Gv_r;
                #pragma unroll
                for (int r=0;r<4;r++){
                    int d = 16*mt + 4*lg + r;
                    float b = qkv_b[2*192 + h*32 + d];
                    float val = acc[r] + ((term==0) ? ((n==0)? -7.f*b : b) : b);
                    dst[d*88 + n] = (__bf16)val;
                }
            }
        }
    }
    __syncthreads();
    for (int j=w; j<9; j+=4){
        int mt = j/3, nt = j - mt*3;
        bf16x8 qr = ldfrag(&Gq_r[(16*mt+lr)*40 + lg*8]);
        bf16x8 qi = ldfrag(&Gqin[(16*mt+lr)*40 + lg*8]);
        bf16x8 kr = ldfrag(&Gk_r[(16*nt+lr)*40 + lg*8]);
        bf16x8 ki = ldfrag(&Gk_i[(16*nt+lr)*40 + lg*8]);
        f32x4 sre = MFMA16(qi, ki, zero4());   // (-Qi).Ki
        sre = MFMA16(qr, kr, sre);             // + Qr.Kr
        f32x4 t1 = MFMA16(qr, ki, zero4());    // Qr.Ki
        f32x4 t2 = MFMA16(qi, kr, zero4());    // (-Qi).Kr
        #pragma unroll
        for (int r=0;r<4;r++){
            float sim = t1[r] - t2[r];
            Smat[(16*mt + 4*lg + r)*52 + 16*nt + lr] =
                SCALE * sqrtf(sre[r]*sre[r] + sim*sim);
        }
    }
    __syncthreads();
    if (tid < 160){
        int row = tid>>2, part = tid&3, e0 = part*10;
        float mx = -1e30f;
        #pragma unroll
        for (int j=0;j<10;j++) mx = fmaxf(mx, Smat[row*52 + e0 + j]);
        mx = fmaxf(mx, __shfl_xor(mx,1));
        mx = fmaxf(mx, __shfl_xor(mx,2));
        float ex[10]; float sum=0.f;
        #pragma unroll
        for (int j=0;j<10;j++){ ex[j] = __expf(Smat[row*52+e0+j]-mx); sum += ex[j]; }
        sum += __shfl_xor(sum,1);
        sum += __shfl_xor(sum,2);
        float inv = 1.f/sum;
        #pragma unroll
        for (int j=0;j<10;j++) Smat[row*52+e0+j] = ex[j]*inv;
    }
    __syncthreads();
    for (int e=tid; e<3072; e+=256){
        int row = e>>6, col = e&63;
        float v = (row<40 && col<40)? Smat[row*52+col] : 0.f;
        P[row*88+col] = (__bf16)v;
    }
    {
        int t2 = tid & 127;
        __bf16* A = (tid<128)? Rt_r : Rt_i;
        int row = t2>>2, c4 = (t2&3)*4;
        *reinterpret_cast<bf16x4*>(A + row*88 + 48 + c4) = z4;
    }
    __syncthreads();
    for (int j=w; j<12; j+=4){
        int term = j/6, r2 = j - term*6;
        int dt = r2/3, nt = r2 - dt*3;
        const __bf16* Gv = term? Gv_i : Gv_r;
        f32x4 acc = zero4();
        #pragma unroll
        for (int ks=0; ks<2; ks++)
            acc = MFMA16(ldfrag(&Gv[(16*dt+lr)*88 + ks*32 + lg*8]),
                         ldfrag(&P [(16*nt+lr)*88 + ks*32 + lg*8]), acc);
        __bf16* dst = term? Rt_i : Rt_r;
        #pragma unroll
        for (int r=0;r<4;r++)
            dst[(16*dt + 4*lg + r)*88 + 16*nt + lr] = (__bf16)acc[r];
    }
    __syncthreads();
    for (int j=w; j<8; j+=4){
        int dt = j>>2, pt = j&3;
        f32x4 acc = zero4();
        #pragma unroll
        for (int ks=0; ks<2; ks++)
            acc = MFMA16(*reinterpret_cast<const bf16x8*>(nSi_g + (16*pt+lr)*64 + ks*32 + lg*8),
                         ldfrag(&Rt_i[(16*dt+lr)*88 + ks*32 + lg*8]), acc);
        #pragma unroll
        for (int ks=0; ks<2; ks++)
            acc = MFMA16(*reinterpret_cast<const bf16x8*>(Ci_g + (16*pt+lr)*64 + ks*32 + lg*8),
                         ldfrag(&Rt_r[(16*dt+lr)*88 + ks*32 + lg*8]), acc);
        #pragma unroll
        for (int r=0;r<4;r++){
            int p = 16*pt + 4*lg + r, d = 16*dt + lr;
            size_t idx = ((size_t)win*64 + p)*192 + h*32 + d;
            Bbuf[idx] += acc[r];
        }
    }
}

// ---------------- K4: proj (MFMA), 128 tokens/block -------------------------
__global__ __launch_bounds__(512,4) void k_proj(const float* __restrict__ Bbuf,
        const float* __restrict__ x, const __bf16* __restrict__ Wpt,
        const float* __restrict__ proj_b, float* __restrict__ X1){
    __shared__ __align__(16) __bf16 xt[128*200];
    __shared__ __align__(16) __bf16 Wt[192*72];
    int tid = threadIdx.x;
    int blk = blockIdx.x;
    {
        int tok = tid>>2, part = tid&3;
        const float* srcp = Bbuf + ((size_t)blk*128 + tok)*192 + part*48;
        #pragma unroll
        for (int i8=0;i8<6;i8++){
            float4 a4 = *reinterpret_cast<const float4*>(srcp + i8*8);
            float4 b4 = *reinterpret_cast<const float4*>(srcp + i8*8 + 4);
            bf16x8 pk;
            pk[0]=(__bf16)a4.x; pk[1]=(__bf16)a4.y; pk[2]=(__bf16)a4.z; pk[3]=(__bf16)a4.w;
            pk[4]=(__bf16)b4.x; pk[5]=(__bf16)b4.y; pk[6]=(__bf16)b4.z; pk[7]=(__bf16)b4.w;
            *reinterpret_cast<bf16x8*>(&xt[tok*200 + part*48 + i8*8]) = pk;
        }
    }
    int lane = tid&63, w = tid>>6, lr = lane&15, lg = lane>>4;
    int rowb = (w>>2)*64, wq = w&3;
    ushort8 wreg[3];
    auto ldW = [&](int kc, ushort8* wr){
        #pragma unroll
        for (int i=0;i<3;i++){
            int e = tid + i*512;
            int j = e>>3, k8 = e&7;
            wr[i] = *reinterpret_cast<const ushort8*>(
                reinterpret_cast<const unsigned short*>(Wpt) + (size_t)j*192 + kc*64 + k8*8);
        }
    };
    auto stW = [&](ushort8* wr){
        #pragma unroll
        for (int i=0;i<3;i++){
            int e = tid + i*512;
            int j = e>>3, k8 = e&7;
            *reinterpret_cast<ushort8*>(reinterpret_cast<unsigned short*>(Wt) + j*72 + k8*8) = wr[i];
        }
    };
    ldW(0, wreg);
    __syncthreads();
    stW(wreg);
    __syncthreads();
    f32x4 acc[4][3];
    #pragma unroll
    for (int m=0;m<4;m++)
        #pragma unroll
        for (int n=0;n<3;n++) acc[m][n] = zero4();
    for (int kc=0; kc<3; kc++){
        if (kc<2) ldW(kc+1, wreg);
        #pragma unroll
        for (int kk=0; kk<2; kk++){
            int ko = kc*64 + kk*32 + lg*8;
            bf16x8 a[4];
            #pragma unroll
            for (int m=0;m<4;m++) a[m] = ldfrag(&xt[(rowb+16*m+lr)*200 + ko]);
            int klo = kk*32 + lg*8;
            bf16x8 bfr[3];
            #pragma unroll
            for (int n=0;n<3;n++) bfr[n] = ldfrag(&Wt[(48*wq+16*n+lr)*72 + klo]);
            #pragma unroll
            for (int m=0;m<4;m++)
                #pragma unroll
                for (int n=0;n<3;n++) acc[m][n] = MFMA16(a[m], bfr[n], acc[m][n]);
        }
        __syncthreads();
        if (kc<2) stW(wreg);
        __syncthreads();
    }
    #pragma unroll
    for (int m=0;m<4;m++)
        #pragma unroll
        for (int r=0;r<4;r++){
            int t = rowb + 16*m + 4*lg + r;          // 0..127
            int win = blk*2 + (t>>6), tt = t&63;
            int bb = win>>8, rem = win&255, wh = rem>>4, wwi = rem&15;
            int p = wh*8 + (tt>>3), q = wwi*8 + (tt&7);
            int hh = (p+SSH)&127, w2 = (q+SSH)&127;
            size_t pixb = (((size_t)bb*128 + hh)*128 + w2)*192;
            #pragma unroll
            for (int n=0;n<3;n++){
                int col = 48*wq + 16*n + lr;
                X1[pixb + col] = acc[m][n][r] + proj_b[col] + x[pixb + col];
            }
        }
}

// ---------------- K5: LN2 + fc1(MFMA) + GELU + fc2(MFMA), 128 tokens/block ---
__global__ __launch_bounds__(512,2) void k_mlp(const float* __restrict__ X1,
        const float* __restrict__ g2, const float* __restrict__ b2v,
        const __bf16* __restrict__ W1t, const float* __restrict__ fc1b,
        const __bf16* __restrict__ W2t, const float* __restrict__ fc2b,
        float* __restrict__ out){
    __shared__ __align__(16) __bf16 xln[128*200];
    __shared__ __align__(16) __bf16 hbuf[128*200];
    __shared__ __align__(16) __bf16 Wt[192*72];
    int tid = threadIdx.x;
    size_t base = (size_t)blockIdx.x*128;
    {
        int tok = tid>>2, part = tid&3;
        const float* srcp = X1 + (base + tok)*192 + part*48;
        float v[48];
        #pragma unroll
        for (int i=0;i<12;i++){
            float4 t4 = *reinterpret_cast<const float4*>(srcp + i*4);
            v[i*4]=t4.x; v[i*4+1]=t4.y; v[i*4+2]=t4.z; v[i*4+3]=t4.w;
        }
        float s=0.f, ss=0.f;
        #pragma unroll
        for (int i=0;i<48;i++){ s+=v[i]; ss+=v[i]*v[i]; }
        s  += __shfl_xor(s,1);  s  += __shfl_xor(s,2);
        ss += __shfl_xor(ss,1); ss += __shfl_xor(ss,2);
        float mean = s*(1.f/192.f);
        float rstd = rsqrtf(ss*(1.f/192.f) - mean*mean + 1e-5f);
        #pragma unroll
        for (int i8=0;i8<6;i8++){
            bf16x8 pk;
            #pragma unroll
            for (int j=0;j<8;j++){
                int ch = part*48 + i8*8 + j;
                pk[j] = (__bf16)((v[i8*8+j]-mean)*rstd*g2[ch] + b2v[ch]);
            }
            *reinterpret_cast<bf16x8*>(&xln[tok*200 + part*48 + i8*8]) = pk;
        }
    }
    int lane = tid&63, w = tid>>6, lr = lane&15, lg = lane>>4;
    int rowb = (w>>2)*64, wq = w&3;
    ushort8 wreg[3];
    auto ldW = [&](int s, ushort8* wr){
        int hc = s/6, inner = s - hc*6;
        int kc = (inner<3)? inner : inner-3;
        const unsigned short* src;
        size_t rowstride;
        size_t off;
        if (inner<3){ src = reinterpret_cast<const unsigned short*>(W1t);
                      rowstride = 192; off = (size_t)(hc*192)*192 + kc*64; }
        else        { src = reinterpret_cast<const unsigned short*>(W2t);
                      rowstride = 768; off = (size_t)hc*192 + kc*64; }
        #pragma unroll
        for (int i=0;i<3;i++){
            int e = tid + i*512;
            int j = e>>3, k8 = e&7;
            wr[i] = *reinterpret_cast<const ushort8*>(src + (size_t)j*rowstride + off + k8*8);
        }
    };
    auto stW = [&](ushort8* wr){
        #pragma unroll
        for (int i=0;i<3;i++){
            int e = tid + i*512;
            int j = e>>3, k8 = e&7;
            *reinterpret_cast<ushort8*>(reinterpret_cast<unsigned short*>(Wt) + j*72 + k8*8) = wr[i];
        }
    };
    ldW(0, wreg);
    __syncthreads();
    stW(wreg);
    __syncthreads();
    f32x4 acc1[4][3], acc2[4][3];
    #pragma unroll
    for (int m=0;m<4;m++)
        #pragma unroll
        for (int n=0;n<3;n++){ acc1[m][n] = zero4(); acc2[m][n] = zero4(); }
    for (int s=0; s<24; s++){
        int hc = s/6, inner = s - hc*6;
        bool fc1 = inner<3;
        int kc = fc1 ? inner : inner-3;
        if (s<23) ldW(s+1, wreg);
        const __bf16* A = fc1 ? xln : hbuf;
        #pragma unroll
        for (int kk=0; kk<2; kk++){
            int ko = kc*64 + kk*32 + lg*8;
            bf16x8 a[4];
            #pragma unroll
            for (int m=0;m<4;m++) a[m] = ldfrag(&A[(rowb+16*m+lr)*200 + ko]);
            int klo = kk*32 + lg*8;
            bf16x8 bfr[3];
            #pragma unroll
            for (int n=0;n<3;n++) bfr[n] = ldfrag(&Wt[(48*wq+16*n+lr)*72 + klo]);
            if (fc1){
                #pragma unroll
                for (int m=0;m<4;m++)
                    #pragma unroll
                    for (int n=0;n<3;n++) acc1[m][n] = MFMA16(a[m], bfr[n], acc1[m][n]);
            } else {
                #pragma unroll
                for (int m=0;m<4;m++)
                    #pragma unroll
                    for (int n=0;n<3;n++) acc2[m][n] = MFMA16(a[m], bfr[n], acc2[m][n]);
            }
        }
        if (inner==2){
            #pragma unroll
            for (int n=0;n<3;n++){
                int jcol = 48*wq + 16*n + lr;
                float b1 = fc1b[hc*192 + jcol];
                #pragma unroll
                for (int m=0;m<4;m++)
                    #pragma unroll
                    for (int r=0;r<4;r++){
                        float xv = acc1[m][n][r] + b1;
                        hbuf[(rowb + 16*m + 4*lg + r)*200 + jcol] = (__bf16)gelu_fast(xv);
                        acc1[m][n][r] = 0.f;
                    }
            }
        }
        __syncthreads();
        if (s<23) stW(wreg);
        __syncthreads();
    }
    #pragma unroll
    for (int n=0;n<3;n++){
        int col = 48*wq + 16*n + lr;
        float b2 = fc2b[col];
        #pragma unroll
        for (int m=0;m<4;m++)
            #pragma unroll
            for (int r=0;r<4;r++){
                size_t t = base + rowb + 16*m + 4*lg + r;
                out[t*192 + col] = acc2[m][n][r] + b2 + X1[t*192 + col];
            }
    }
}

extern "C" void kernel_launch(void* const* d_in, const int* in_sizes, int n_in,
                              void* d_out, int out_size, void* d_ws, size_t ws_size,
                              hipStream_t stream) {
    const float* x     = (const float*)d_in[0];
    const float* mask  = (const float*)d_in[1];
    const float* n1g   = (const float*)d_in[2];
    const float* n1b   = (const float*)d_in[3];
    const float* qkvw  = (const float*)d_in[4];
    const float* qkvb  = (const float*)d_in[5];
    const float* relt  = (const float*)d_in[6];
    const float* projw = (const float*)d_in[7];
    const float* projb = (const float*)d_in[8];
    const float* n2g   = (const float*)d_in[9];
    const float* n2b   = (const float*)d_in[10];
    const float* fc1w  = (const float*)d_in[11];
    const float* fc1b  = (const float*)d_in[12];
    const float* fc2w  = (const float*)d_in[13];
    const float* fc2b  = (const float*)d_in[14];
    float* out = (float*)d_out;

    char* wsb = (char*)d_ws;
    __bf16* Sb  = (__bf16*)wsb;                        // 150,994,944 B
    float*  X1  = (float*)(wsb + 150994944);           // 100,663,296 B
    __bf16* Wqt = (__bf16*)(wsb + 251658240);          //    221,184 B
    __bf16* Wpt = (__bf16*)(wsb + 251879424);          //     73,728 B
    __bf16* W1t = (__bf16*)(wsb + 251953152);          //    294,912 B
    __bf16* W2t = (__bf16*)(wsb + 252248064);          //    294,912 B
    __bf16* Fre = (__bf16*)(wsb + 252542976);          //      6,144 B
    __bf16* Fim = (__bf16*)(wsb + 252549120);          //      6,144 B
    __bf16* Ci  = (__bf16*)(wsb + 252555264);          //      8,192 B
    __bf16* nSi = (__bf16*)(wsb + 252563456);          //      8,192 B

    k_prep   <<<576,   256, 0, stream>>>(qkvw, projw, fc1w, fc2w, Wqt, Wpt, W1t, W2t,
                                         Fre, Fim, Ci, nSi);
    k_qkv    <<<1024,  512, 0, stream>>>(x, n1g, n1b, Wqt, qkvb, Sb);
    k_spatial<<<2048,  256, 0, stream>>>(Sb, relt, mask, out);
    k_fattn  <<<12288, 256, 0, stream>>>(Sb, qkvb, Fre, Fim, Ci, nSi, out);
    k_proj   <<<1024,  512, 0, stream>>>(out, x, Wpt, projb, X1);
    k_mlp    <<<1024,  512, 0, stream>>>(X1, n2g, n2b, W1t, fc1b, W2t, fc2b, out);
}